// Round 8
// baseline (360.176 us; speedup 1.0000x reference)
//
#include <hip/hip_runtime.h>
#include <hip/hip_bf16.h>

#define B_ 4
#define S_ 1024
#define E_ 1280
#define H_ 16
#define D_ 80
#define M_ (B_*S_)   // 4096

typedef __hip_bfloat16 bf16;
using bf16x8 = __attribute__((ext_vector_type(8))) short;  // 8 bf16 = 4 VGPRs
using f32x4  = __attribute__((ext_vector_type(4))) float;  // MFMA C/D frag

__device__ __forceinline__ float b2f(bf16 x){ return __bfloat162float(x); }
__device__ __forceinline__ bf16  f2b(float x){ return __float2bfloat16(x); }
__device__ __forceinline__ void  stf(float* p, float v){ *p = v; }
__device__ __forceinline__ void  stf(bf16*  p, float v){ *p = f2b(v); }

__device__ __forceinline__ void gload_lds16(const void* g, void* l) {
    __builtin_amdgcn_global_load_lds(
        (const __attribute__((address_space(1))) unsigned int*)g,
        (__attribute__((address_space(3))) unsigned int*)l, 16, 0, 0);
}

// fp32 -> bf16 conversion, 8 elems/thread. blockIdx.y selects segment.
__global__ __launch_bounds__(256) void cvt_kernel(
    const float* __restrict__ s0, const float* __restrict__ s1,
    const float* __restrict__ s2, const float* __restrict__ s3,
    const float* __restrict__ s4,
    bf16* __restrict__ d0, bf16* __restrict__ d1, bf16* __restrict__ d2,
    bf16* __restrict__ d3, bf16* __restrict__ d4,
    int n0, int n1)
{
    const float* s; bf16* d; int n;
    switch (blockIdx.y) {
        case 0: s = s0; d = d0; n = n0; break;
        case 1: s = s1; d = d1; n = n1; break;
        case 2: s = s2; d = d2; n = n1; break;
        case 3: s = s3; d = d3; n = n1; break;
        default: s = s4; d = d4; n = n1; break;
    }
    int i = (blockIdx.x * 256 + threadIdx.x) * 8;
    if (i >= n) return;
    float4 a = *(const float4*)(s + i);
    float4 b = *(const float4*)(s + i + 4);
    bf16 t[8];
    t[0]=f2b(a.x); t[1]=f2b(a.y); t[2]=f2b(a.z); t[3]=f2b(a.w);
    t[4]=f2b(b.x); t[5]=f2b(b.y); t[6]=f2b(b.z); t[7]=f2b(b.w);
    *(uint4*)(d + i) = *(const uint4*)t;
}

// m97-style MFMA GEMM: C[m,n] = sum_k A[m,k]*W[n,k] + bias[n]
// VT_OUT: mat==2 (V) stores transposed as VT[btok][h][d][key].
template<typename TC, bool VT_OUT>
__global__ __launch_bounds__(256) void mfma_gemm_bt(
    const bf16* __restrict__ A,
    const bf16* __restrict__ W0, const bf16* __restrict__ W1, const bf16* __restrict__ W2,
    const float* __restrict__ b0, const float* __restrict__ b1, const float* __restrict__ b2,
    TC* __restrict__ C0, TC* __restrict__ C1, TC* __restrict__ C2,
    int K, int N, int ntiles)
{
    const int mat = blockIdx.y / ntiles;
    const int bn  = (blockIdx.y % ntiles) * 128;
    const int bm  = blockIdx.x * 128;
    const bf16* W; const float* bias; TC* C;
    if (mat == 0)      { W = W0; bias = b0; C = C0; }
    else if (mat == 1) { W = W1; bias = b1; C = C1; }
    else               { W = W2; bias = b2; C = C2; }

    __shared__ bf16 As[128][32];
    __shared__ bf16 Ws[128][32];

    const int tid  = threadIdx.x;
    const int lane = tid & 63;
    const int wv   = tid >> 6;
    const int wm   = (wv & 1) * 64;
    const int wn   = (wv >> 1) * 64;
    const int srow = wv * 16 + (lane >> 2);
    const int scol = (lane & 3) * 8;

    f32x4 acc[4][4] = {};

    for (int k0 = 0; k0 < K; k0 += 32) {
        __syncthreads();
        gload_lds16(A + (size_t)(bm + srow)      * K + k0 + scol, &As[wv*16][0]);
        gload_lds16(A + (size_t)(bm + 64 + srow) * K + k0 + scol, &As[64 + wv*16][0]);
        gload_lds16(W + (size_t)(bn + srow)      * K + k0 + scol, &Ws[wv*16][0]);
        gload_lds16(W + (size_t)(bn + 64 + srow) * K + k0 + scol, &Ws[64 + wv*16][0]);
        __syncthreads();

        const int fr = lane & 15;
        const int kq = (lane >> 4) * 8;
        bf16x8 af[4], wf[4];
        #pragma unroll
        for (int t = 0; t < 4; t++) {
            af[t] = *(const bf16x8*)&As[wm + t*16 + fr][kq];
            wf[t] = *(const bf16x8*)&Ws[wn + t*16 + fr][kq];
        }
        #pragma unroll
        for (int mt = 0; mt < 4; mt++)
            #pragma unroll
            for (int nt = 0; nt < 4; nt++)
                acc[mt][nt] = __builtin_amdgcn_mfma_f32_16x16x32_bf16(
                    af[mt], wf[nt], acc[mt][nt], 0, 0, 0);
    }

    const int col_l = lane & 15;
    const int row_l = (lane >> 4) * 4;

    if (VT_OUT && mat == 2) {
        const int btok = bm >> 10;
        const int keyb = (bm & 1023) + wm + row_l;
        #pragma unroll
        for (int nt = 0; nt < 4; nt++) {
            const int n = bn + wn + nt*16 + col_l;
            const float bv = bias[n];
            const int hh = n / 80, dd = n % 80;
            bf16* vbase = (bf16*)C + ((size_t)(btok*H_ + hh)*D_ + dd)*S_ + keyb;
            #pragma unroll
            for (int mt = 0; mt < 4; mt++) {
                union { bf16 h[4]; uint2 u; } t4;
                #pragma unroll
                for (int r = 0; r < 4; r++) t4.h[r] = f2b(acc[mt][nt][r] + bv);
                *(uint2*)&vbase[mt*16] = t4.u;
            }
        }
    } else {
        #pragma unroll
        for (int nt = 0; nt < 4; nt++) {
            const int n = bn + wn + nt*16 + col_l;
            const float bv = bias[n];
            #pragma unroll
            for (int mt = 0; mt < 4; mt++) {
                #pragma unroll
                for (int r = 0; r < 4; r++) {
                    const int m = bm + wm + mt*16 + row_l + r;
                    stf(&C[(size_t)m * N + n], acc[mt][nt][r] + bv);
                }
            }
        }
    }
}

// rope from pointers (used for Q staging): lo=dims j..j+8 (j<40), hi=j+40..
__device__ __forceinline__ void rope8(const bf16* lo, const bf16* hi,
                                      const float* cp, const float* sp,
                                      float mul, uint4* out_lo, uint4* out_hi)
{
    union { uint4 u; bf16 h[8]; } li, hi_, lo_o, hi_o;
    li.u  = *(const uint4*)lo;
    hi_.u = *(const uint4*)hi;
    #pragma unroll
    for (int u = 0; u < 8; u++) {
        float x1 = b2f(li.h[u]), x2 = b2f(hi_.h[u]);
        float c = cp[u], s = sp[u];
        lo_o.h[u] = f2b((x1*c - x2*s) * mul);
        hi_o.h[u] = f2b((x2*c + x1*s) * mul);
    }
    *out_lo = lo_o.u;
    *out_hi = hi_o.u;
}

// rope from registers (used for pipelined K staging)
__device__ __forceinline__ void rope8r(uint4 lo, uint4 hi,
                                       float4 c0, float4 c1, float4 s0, float4 s1,
                                       uint4* out_lo, uint4* out_hi)
{
    union { uint4 u; bf16 h[8]; } li, hi_, lo_o, hi_o;
    li.u = lo; hi_.u = hi;
    float cc[8] = {c0.x,c0.y,c0.z,c0.w,c1.x,c1.y,c1.z,c1.w};
    float ss[8] = {s0.x,s0.y,s0.z,s0.w,s1.x,s1.y,s1.z,s1.w};
    #pragma unroll
    for (int u = 0; u < 8; u++) {
        float x1 = b2f(li.h[u]), x2 = b2f(hi_.h[u]);
        lo_o.h[u] = f2b(x1*cc[u] - x2*ss[u]);
        hi_o.h[u] = f2b(x2*cc[u] + x1*ss[u]);
    }
    *out_lo = lo_o.u;
    *out_hi = hi_o.u;
}

// Prefetch state for one K/V tile (registers)
struct KPre {
    uint4  lo0, hi0, lo1, hi1;               // K data: task tid, task tid+256 (tid<64)
    float4 c00, c01, s00, s01;               // trig task 0
    float4 c10, c11, s10, s11;               // trig task 1
    uint4  v0, v1, v2;                       // VT chunks tid, tid+256, tid+512 (tid<128)
};

// MFMA flash attention v4 — software-pipelined K-loop.
// 1-D grid, XCD-swizzled: L = g + 64*qt (all 8 q-tiles of a (b,h) share L%8).
// Double-buffered K/V in LDS; prefetch depth 2 tiles via registers; ONE
// barrier per k-tile iteration. RoPE fused into staging.
__global__ __launch_bounds__(256, 2) void attn_mfma(
    const bf16* __restrict__ q, const bf16* __restrict__ k, const bf16* __restrict__ vt,
    const int* __restrict__ cu, const float* __restrict__ cosp, const float* __restrict__ sinp,
    bf16* __restrict__ o)
{
    // A: Ks@0 (64x100x2=12800) VTs@12800 (80x68x2=10880) | B: @23680 same | PT: @47360 + wv*4352
    __shared__ __align__(16) char smem[64768];
    bf16* KsA  = (bf16*)smem;
    bf16* VTsA = (bf16*)(smem + 12800);
    bf16* KsB  = (bf16*)(smem + 23680);
    bf16* VTsB = (bf16*)(smem + 23680 + 12800);

    const int L  = blockIdx.x;
    const int qt = L >> 6;
    const int g  = L & 63;
    const int b  = g >> 4;
    const int h  = g & 15;

    const int tid = threadIdx.x;
    const int lane = tid & 63, wv = tid >> 6;
    const int quad = lane >> 4, l15 = lane & 15;
    const int q0 = qt * 128;
    const int len = cu[b + 1] - cu[b];
    const float scale = 0.11180339887498949f;  // 1/sqrt(80), folded into Q

    const int trow = tid / 5, tpc = tid % 5;           // K-task 0 coords (all threads)
    const int trow1 = (tid + 256) / 5, tpc1 = (tid + 256) % 5;  // K-task 1 (tid<64)

    // ---- prefetch issue for tile kt
    KPre P;
    auto issueK = [&](int kt) {
        {
            int s = kt*64 + trow;
            const bf16* src = k + ((size_t)b*S_ + s)*E_ + h*D_ + tpc*8;
            P.lo0 = *(const uint4*)src;
            P.hi0 = *(const uint4*)(src + 40);
            const float* cp = cosp + s*D_ + tpc*8;
            const float* sp = sinp + s*D_ + tpc*8;
            P.c00 = *(const float4*)cp;  P.c01 = *(const float4*)(cp + 4);
            P.s00 = *(const float4*)sp;  P.s01 = *(const float4*)(sp + 4);
        }
        if (tid < 64) {
            int s = kt*64 + trow1;
            const bf16* src = k + ((size_t)b*S_ + s)*E_ + h*D_ + tpc1*8;
            P.lo1 = *(const uint4*)src;
            P.hi1 = *(const uint4*)(src + 40);
            const float* cp = cosp + s*D_ + tpc1*8;
            const float* sp = sinp + s*D_ + tpc1*8;
            P.c10 = *(const float4*)cp;  P.c11 = *(const float4*)(cp + 4);
            P.s10 = *(const float4*)sp;  P.s11 = *(const float4*)(sp + 4);
        }
        const bf16* vb = vt + ((size_t)(b*H_ + h)*D_)*S_ + kt*64;
        P.v0 = *(const uint4*)(vb + (size_t)(tid >> 3)*S_ + (tid & 7)*8);
        {
            int c = tid + 256;
            P.v1 = *(const uint4*)(vb + (size_t)(c >> 3)*S_ + (c & 7)*8);
        }
        if (tid < 128) {
            int c = tid + 512;
            P.v2 = *(const uint4*)(vb + (size_t)(c >> 3)*S_ + (c & 7)*8);
        }
    };
    // ---- commit prefetched tile to LDS buffer (rope on K)
    auto commitK = [&](bf16* Ksb, bf16* VTsb) {
        uint4 olo, ohi;
        rope8r(P.lo0, P.hi0, P.c00, P.c01, P.s00, P.s01, &olo, &ohi);
        *(uint4*)&Ksb[trow*100 + tpc*8]      = olo;
        *(uint4*)&Ksb[trow*100 + tpc*8 + 40] = ohi;
        if (tid < 64) {
            rope8r(P.lo1, P.hi1, P.c10, P.c11, P.s10, P.s11, &olo, &ohi);
            *(uint4*)&Ksb[trow1*100 + tpc1*8]      = olo;
            *(uint4*)&Ksb[trow1*100 + tpc1*8 + 40] = ohi;
        }
        *(uint4*)&VTsb[(tid >> 3)*68 + (tid & 7)*8] = P.v0;
        { int c = tid + 256; *(uint4*)&VTsb[(c >> 3)*68 + (c & 7)*8] = P.v1; }
        if (tid < 128) { int c = tid + 512; *(uint4*)&VTsb[(c >> 3)*68 + (c & 7)*8] = P.v2; }
    };

    issueK(0);

    // zero pad cols 80..95 in both K buffers (doubles as Q pad for the staging region)
    if (tid < 128) {
        uint4 z = make_uint4(0,0,0,0);
        int row = tid >> 1, c8 = tid & 1;
        *(uint4*)&KsA[row*100 + 80 + c8*8] = z;
        *(uint4*)&KsB[row*100 + 80 + c8*8] = z;
    }

    // ---- Q staging through KsA region, two halves of 64 rows
    bf16x8 qf[2][3];
    auto stageQ = [&](int hh) {
        #pragma unroll
        for (int t = tid; t < 320; t += 256) {
            int row = t / 5, pc = t % 5;
            int s = q0 + hh*64 + row;
            const bf16* src = q + ((size_t)b*S_ + s)*E_ + h*D_ + pc*8;
            uint4 olo, ohi;
            rope8(src, src + 40, cosp + s*D_ + pc*8, sinp + s*D_ + pc*8, scale, &olo, &ohi);
            *(uint4*)&KsA[row*100 + pc*8]      = olo;
            *(uint4*)&KsA[row*100 + pc*8 + 40] = ohi;
        }
    };
    auto readQf = [&]() {
        #pragma unroll
        for (int m = 0; m < 2; m++)
            #pragma unroll
            for (int ks = 0; ks < 3; ks++)
                qf[m][ks] = *(const bf16x8*)&KsA[((wv & 1)*32 + m*16 + l15)*100 + ks*32 + quad*8];
    };

    stageQ(0);
    __syncthreads();
    if (wv < 2) readQf();
    __syncthreads();
    stageQ(1);
    __syncthreads();
    if (wv >= 2) readQf();
    __syncthreads();
    commitK(KsA, VTsA);
    issueK(1);
    __syncthreads();

    float m_r[2][4], l_r[2][4];
    #pragma unroll
    for (int m = 0; m < 2; m++)
        #pragma unroll
        for (int r = 0; r < 4; r++) { m_r[m][r] = -1e30f; l_r[m][r] = 0.f; }
    f32x4 o_acc[2][5] = {};
    bf16* PT = (bf16*)(smem + 47360 + wv * 4352);   // [32][68]

    const bool q_full = (q0 + 128) <= len;

    for (int kt = 0; kt < 16; kt++) {
        const bf16* Ksc  = (kt & 1) ? KsB  : KsA;
        const bf16* VTsc = (kt & 1) ? VTsB : VTsA;
        bf16* Ksn  = (kt & 1) ? KsA  : KsB;
        bf16* VTsn = (kt & 1) ? VTsA : VTsB;

        // ---- QK^T: K-frags shared across the 2 m-tiles
        f32x4 s4[2][4];
        #pragma unroll
        for (int nt = 0; nt < 4; nt++) {
            f32x4 a0 = {}, a1 = {};
            #pragma unroll
            for (int ks = 0; ks < 3; ks++) {
                bf16x8 kf = *(const bf16x8*)&Ksc[(nt*16 + l15)*100 + ks*32 + quad*8];
                a0 = __builtin_amdgcn_mfma_f32_16x16x32_bf16(qf[0][ks], kf, a0, 0, 0, 0);
                a1 = __builtin_amdgcn_mfma_f32_16x16x32_bf16(qf[1][ks], kf, a1, 0, 0, 0);
            }
            s4[0][nt] = a0; s4[1][nt] = a1;
        }

        const bool full = q_full && (kt*64 + 64) <= len;
        bool vk[4];
        #pragma unroll
        for (int nt = 0; nt < 4; nt++) vk[nt] = (kt*64 + nt*16 + l15) < len;

        // ---- online softmax per m-tile (rows quad*4+r, wave-exclusive)
        #pragma unroll
        for (int m = 0; m < 2; m++) {
            float sv[4][4];
            if (full) {
                #pragma unroll
                for (int r = 0; r < 4; r++)
                    #pragma unroll
                    for (int nt = 0; nt < 4; nt++)
                        sv[nt][r] = s4[m][nt][r];
            } else {
                #pragma unroll
                for (int r = 0; r < 4; r++) {
                    const bool vq = (q0 + wv*32 + m*16 + quad*4 + r) < len;
                    #pragma unroll
                    for (int nt = 0; nt < 4; nt++)
                        sv[nt][r] = (vq && vk[nt]) ? s4[m][nt][r] : -1e9f;
                }
            }
            float rmax[4];
            #pragma unroll
            for (int r = 0; r < 4; r++)
                rmax[r] = fmaxf(fmaxf(sv[0][r], sv[1][r]), fmaxf(sv[2][r], sv[3][r]));
            #pragma unroll
            for (int st = 1; st < 16; st <<= 1)
                #pragma unroll
                for (int r = 0; r < 4; r++)
                    rmax[r] = fmaxf(rmax[r], __shfl_xor(rmax[r], st, 64));
            float mnew[4], alpha[4], rsum[4], p[4][4];
            #pragma unroll
            for (int r = 0; r < 4; r++) {
                mnew[r]  = fmaxf(m_r[m][r], rmax[r]);
                alpha[r] = __expf(m_r[m][r] - mnew[r]);
                float a = 0.f;
                #pragma unroll
                for (int nt = 0; nt < 4; nt++) { p[nt][r] = __expf(sv[nt][r] - mnew[r]); a += p[nt][r]; }
                rsum[r] = a;
            }
            #pragma unroll
            for (int st = 1; st < 16; st <<= 1)
                #pragma unroll
                for (int r = 0; r < 4; r++)
                    rsum[r] += __shfl_xor(rsum[r], st, 64);
            #pragma unroll
            for (int r = 0; r < 4; r++) {
                l_r[m][r] = l_r[m][r] * alpha[r] + rsum[r];
                m_r[m][r] = mnew[r];
            }
            #pragma unroll
            for (int dt = 0; dt < 5; dt++)
                #pragma unroll
                for (int r = 0; r < 4; r++)
                    o_acc[m][dt][r] *= alpha[r];
            // P (C-layout) -> PT (A-layout)
            #pragma unroll
            for (int nt = 0; nt < 4; nt++)
                #pragma unroll
                for (int r = 0; r < 4; r++)
                    PT[(m*16 + quad*4 + r)*68 + nt*16 + l15] = f2b(p[nt][r]);
        }

        // ---- PV: V B-frags b128 from VTs, shared across m-tiles
        bf16x8 pa[2][2];
        #pragma unroll
        for (int m = 0; m < 2; m++)
            #pragma unroll
            for (int ks = 0; ks < 2; ks++)
                pa[m][ks] = *(const bf16x8*)&PT[(m*16 + l15)*68 + ks*32 + quad*8];
        #pragma unroll
        for (int dt = 0; dt < 5; dt++) {
            #pragma unroll
            for (int ks = 0; ks < 2; ks++) {
                bf16x8 vf = *(const bf16x8*)&VTsc[(dt*16 + l15)*68 + ks*32 + quad*8];
                o_acc[0][dt] = __builtin_amdgcn_mfma_f32_16x16x32_bf16(pa[0][ks], vf, o_acc[0][dt], 0, 0, 0);
                o_acc[1][dt] = __builtin_amdgcn_mfma_f32_16x16x32_bf16(pa[1][ks], vf, o_acc[1][dt], 0, 0, 0);
            }
        }

        // ---- pipeline: commit kt+1 (prefetched) to the other buffer, issue kt+2
        if (kt < 15) commitK(Ksn, VTsn);
        if (kt < 14) issueK(kt + 2);
        __syncthreads();
    }

    // ---- epilogue
    #pragma unroll
    for (int m = 0; m < 2; m++)
        #pragma unroll
        for (int r = 0; r < 4; r++) {
            const float inv = 1.0f / l_r[m][r];
            size_t row_g = (size_t)(b*S_ + q0 + wv*32 + m*16 + quad*4 + r);
            #pragma unroll
            for (int dt = 0; dt < 5; dt++)
                o[row_g*E_ + h*D_ + dt*16 + l15] = f2b(o_acc[m][dt][r] * inv);
        }
}

extern "C" void kernel_launch(void* const* d_in, const int* in_sizes, int n_in,
                              void* d_out, int out_size, void* d_ws, size_t ws_size,
                              hipStream_t stream)
{
    const float* x    = (const float*)d_in[0];
    const int*   cu   = (const int*)  d_in[1];
    const float* cosp = (const float*)d_in[2];
    const float* sinp = (const float*)d_in[3];
    const float* wq   = (const float*)d_in[4];
    const float* bq   = (const float*)d_in[5];
    const float* wk   = (const float*)d_in[6];
    const float* bk   = (const float*)d_in[7];
    const float* wv   = (const float*)d_in[8];
    const float* bv   = (const float*)d_in[9];
    const float* wo   = (const float*)d_in[10];
    const float* bo   = (const float*)d_in[11];
    float* out = (float*)d_out;

    bf16* q   = (bf16*)d_ws;
    bf16* kk  = q   + (size_t)M_ * E_;
    bf16* vt  = kk  + (size_t)M_ * E_;   // transposed V: [B][H][D][S]
    bf16* ao  = vt  + (size_t)M_ * E_;
    bf16* xb  = ao  + (size_t)M_ * E_;
    bf16* wqb = xb  + (size_t)M_ * E_;
    bf16* wkb = wqb + (size_t)E_ * E_;
    bf16* wvb = wkb + (size_t)E_ * E_;
    bf16* wob = wvb + (size_t)E_ * E_;

    // 0) convert x + 4 weight matrices to bf16
    cvt_kernel<<<dim3(2560, 5), 256, 0, stream>>>(
        x, wq, wk, wv, wo, xb, wqb, wkb, wvb, wob, M_*E_, E_*E_);

    // 1) QKV projection (MFMA), bias fused; V written transposed.
    //    q/k hold PRE-rope values (rope fused into attention staging).
    mfma_gemm_bt<bf16, true><<<dim3(M_/128, 30), 256, 0, stream>>>(
        xb, wqb, wkb, wvb, bq, bk, bv, q, kk, vt, E_, E_, 10);

    // 2) MFMA flash attention (pipelined, XCD-swizzled, fused RoPE)
    attn_mfma<<<512, 256, 0, stream>>>(q, kk, vt, cu, cosp, sinp, ao);

    // 3) output projection (MFMA), fp32 out, bias fused
    mfma_gemm_bt<float, false><<<dim3(M_/128, 10), 256, 0, stream>>>(
        ao, wob, wob, wob, bo, bo, bo, out, out, out, E_, E_, 10);
}

// Round 9
// 341.008 us; speedup vs baseline: 1.0562x; 1.0562x over previous
//
#include <hip/hip_runtime.h>
#include <hip/hip_bf16.h>

#define B_ 4
#define S_ 1024
#define E_ 1280
#define H_ 16
#define D_ 80
#define M_ (B_*S_)   // 4096

typedef __hip_bfloat16 bf16;
using bf16x8 = __attribute__((ext_vector_type(8))) short;  // 8 bf16 = 4 VGPRs
using f32x4  = __attribute__((ext_vector_type(4))) float;  // MFMA C/D frag

__device__ __forceinline__ float b2f(bf16 x){ return __bfloat162float(x); }
__device__ __forceinline__ bf16  f2b(float x){ return __float2bfloat16(x); }
__device__ __forceinline__ void  stf(float* p, float v){ *p = v; }
__device__ __forceinline__ void  stf(bf16*  p, float v){ *p = f2b(v); }

__device__ __forceinline__ void gload_lds16(const void* g, void* l) {
    __builtin_amdgcn_global_load_lds(
        (const __attribute__((address_space(1))) unsigned int*)g,
        (__attribute__((address_space(3))) unsigned int*)l, 16, 0, 0);
}

// fp32 -> bf16 conversion, 8 elems/thread. blockIdx.y selects segment.
__global__ __launch_bounds__(256) void cvt_kernel(
    const float* __restrict__ s0, const float* __restrict__ s1,
    const float* __restrict__ s2, const float* __restrict__ s3,
    const float* __restrict__ s4,
    bf16* __restrict__ d0, bf16* __restrict__ d1, bf16* __restrict__ d2,
    bf16* __restrict__ d3, bf16* __restrict__ d4,
    int n0, int n1)
{
    const float* s; bf16* d; int n;
    switch (blockIdx.y) {
        case 0: s = s0; d = d0; n = n0; break;
        case 1: s = s1; d = d1; n = n1; break;
        case 2: s = s2; d = d2; n = n1; break;
        case 3: s = s3; d = d3; n = n1; break;
        default: s = s4; d = d4; n = n1; break;
    }
    int i = (blockIdx.x * 256 + threadIdx.x) * 8;
    if (i >= n) return;
    float4 a = *(const float4*)(s + i);
    float4 b = *(const float4*)(s + i + 4);
    bf16 t[8];
    t[0]=f2b(a.x); t[1]=f2b(a.y); t[2]=f2b(a.z); t[3]=f2b(a.w);
    t[4]=f2b(b.x); t[5]=f2b(b.y); t[6]=f2b(b.z); t[7]=f2b(b.w);
    *(uint4*)(d + i) = *(const uint4*)t;
}

// m97-style MFMA GEMM: C[m,n] = sum_k A[m,k]*W[n,k] + bias[n]
// VT_OUT: mat==2 (V) stores transposed as VT[btok][h][d][key].
template<typename TC, bool VT_OUT>
__global__ __launch_bounds__(256) void mfma_gemm_bt(
    const bf16* __restrict__ A,
    const bf16* __restrict__ W0, const bf16* __restrict__ W1, const bf16* __restrict__ W2,
    const float* __restrict__ b0, const float* __restrict__ b1, const float* __restrict__ b2,
    TC* __restrict__ C0, TC* __restrict__ C1, TC* __restrict__ C2,
    int K, int N, int ntiles)
{
    const int mat = blockIdx.y / ntiles;
    const int bn  = (blockIdx.y % ntiles) * 128;
    const int bm  = blockIdx.x * 128;
    const bf16* W; const float* bias; TC* C;
    if (mat == 0)      { W = W0; bias = b0; C = C0; }
    else if (mat == 1) { W = W1; bias = b1; C = C1; }
    else               { W = W2; bias = b2; C = C2; }

    __shared__ bf16 As[128][32];
    __shared__ bf16 Ws[128][32];

    const int tid  = threadIdx.x;
    const int lane = tid & 63;
    const int wv   = tid >> 6;
    const int wm   = (wv & 1) * 64;
    const int wn   = (wv >> 1) * 64;
    const int srow = wv * 16 + (lane >> 2);
    const int scol = (lane & 3) * 8;

    f32x4 acc[4][4] = {};

    for (int k0 = 0; k0 < K; k0 += 32) {
        __syncthreads();
        gload_lds16(A + (size_t)(bm + srow)      * K + k0 + scol, &As[wv*16][0]);
        gload_lds16(A + (size_t)(bm + 64 + srow) * K + k0 + scol, &As[64 + wv*16][0]);
        gload_lds16(W + (size_t)(bn + srow)      * K + k0 + scol, &Ws[wv*16][0]);
        gload_lds16(W + (size_t)(bn + 64 + srow) * K + k0 + scol, &Ws[64 + wv*16][0]);
        __syncthreads();

        const int fr = lane & 15;
        const int kq = (lane >> 4) * 8;
        bf16x8 af[4], wf[4];
        #pragma unroll
        for (int t = 0; t < 4; t++) {
            af[t] = *(const bf16x8*)&As[wm + t*16 + fr][kq];
            wf[t] = *(const bf16x8*)&Ws[wn + t*16 + fr][kq];
        }
        #pragma unroll
        for (int mt = 0; mt < 4; mt++)
            #pragma unroll
            for (int nt = 0; nt < 4; nt++)
                acc[mt][nt] = __builtin_amdgcn_mfma_f32_16x16x32_bf16(
                    af[mt], wf[nt], acc[mt][nt], 0, 0, 0);
    }

    const int col_l = lane & 15;
    const int row_l = (lane >> 4) * 4;

    if (VT_OUT && mat == 2) {
        const int btok = bm >> 10;
        const int keyb = (bm & 1023) + wm + row_l;
        #pragma unroll
        for (int nt = 0; nt < 4; nt++) {
            const int n = bn + wn + nt*16 + col_l;
            const float bv = bias[n];
            const int hh = n / 80, dd = n % 80;
            bf16* vbase = (bf16*)C + ((size_t)(btok*H_ + hh)*D_ + dd)*S_ + keyb;
            #pragma unroll
            for (int mt = 0; mt < 4; mt++) {
                union { bf16 h[4]; uint2 u; } t4;
                #pragma unroll
                for (int r = 0; r < 4; r++) t4.h[r] = f2b(acc[mt][nt][r] + bv);
                *(uint2*)&vbase[mt*16] = t4.u;
            }
        }
    } else {
        #pragma unroll
        for (int nt = 0; nt < 4; nt++) {
            const int n = bn + wn + nt*16 + col_l;
            const float bv = bias[n];
            #pragma unroll
            for (int mt = 0; mt < 4; mt++) {
                #pragma unroll
                for (int r = 0; r < 4; r++) {
                    const int m = bm + wm + mt*16 + row_l + r;
                    stf(&C[(size_t)m * N + n], acc[mt][nt][r] + bv);
                }
            }
        }
    }
}

// rope helper: lo=dims j..j+8 (j<40), hi=j+40.. ; out_lo = x1*c - x2*s, out_hi = x2*c + x1*s
__device__ __forceinline__ void rope8(const bf16* lo, const bf16* hi,
                                      const float* cp, const float* sp,
                                      float mul, uint4* out_lo, uint4* out_hi)
{
    union { uint4 u; bf16 h[8]; } li, hi_, lo_o, hi_o;
    li.u  = *(const uint4*)lo;
    hi_.u = *(const uint4*)hi;
    #pragma unroll
    for (int u = 0; u < 8; u++) {
        float x1 = b2f(li.h[u]), x2 = b2f(hi_.h[u]);
        float c = cp[u], s = sp[u];
        lo_o.h[u] = f2b((x1*c - x2*s) * mul);
        hi_o.h[u] = f2b((x2*c + x1*s) * mul);
    }
    *out_lo = lo_o.u;
    *out_hi = hi_o.u;
}

// MFMA flash attention v5 — R7 skeleton + MAX-FREE softmax.
// p = exp(s) directly (scores are O(1); masked keys -> exp(-1e9) = 0; invalid
// q-rows -> s=0 for all keys = uniform, matching reference). Denominator l is
// accumulated BY the PV MFMA via a 6th V d-tile whose col 0 is all-ones
// (VTs rows 80..95: row 80 = 1, rest 0) -> l = o_acc[5] col 0. No shfl
// reductions, no alpha-rescale, no m/l chains in the loop.
// 1-D grid, XCD-swizzled: L = g + 64*qt. RoPE fused into staging.
__global__ __launch_bounds__(256, 3) void attn_mfma(
    const bf16* __restrict__ q, const bf16* __restrict__ k, const bf16* __restrict__ vt,
    const int* __restrict__ cu, const float* __restrict__ cosp, const float* __restrict__ sinp,
    bf16* __restrict__ o)
{
    // Qs[128][100] @0 (25600 B) | Ks[64][100] @25600 (12800 B) | VTs[96][68] @38400 (13056 B)
    // PT per-wave [32][68] (4352 B) aliases Qs (Q frags in regs before first PT write).
    __shared__ __align__(16) char smem[51456];
    bf16* Qs  = (bf16*)smem;
    bf16* Ks  = (bf16*)(smem + 25600);
    bf16* VTs = (bf16*)(smem + 38400);

    const int L  = blockIdx.x;
    const int qt = L >> 6;
    const int g  = L & 63;
    const int b  = g >> 4;
    const int h  = g & 15;

    const int tid = threadIdx.x;
    const int lane = tid & 63, wv = tid >> 6;
    const int quad = lane >> 4, l15 = lane & 15;
    const int q0 = qt * 128;
    const int len = cu[b + 1] - cu[b];
    const float scale = 0.11180339887498949f;  // 1/sqrt(80), folded into Q

    // ---- stage Q with fused RoPE (pre-scaled): 128 rows x 5 pair-chunks = 640 tasks
    #pragma unroll
    for (int i = 0; i < 3; i++) {
        int c = tid + i * 256;
        if (c < 640) {
            int row = c / 5, pc = c % 5;
            int s = q0 + row;
            const bf16* src = q + (size_t)(b*S_ + s)*E_ + h*D_ + pc*8;
            uint4 olo, ohi;
            rope8(src, src + 40, cosp + s*D_ + pc*8, sinp + s*D_ + pc*8, scale, &olo, &ohi);
            *(uint4*)&Qs[row*100 + pc*8]      = olo;
            *(uint4*)&Qs[row*100 + pc*8 + 40] = ohi;
        }
    }
    // zero-pad cols 80..95 (Qs: 256 chunks, Ks: 128 chunks)
    {
        uint4 z = make_uint4(0,0,0,0);
        int row = tid >> 1, c8 = tid & 1;
        *(uint4*)&Qs[row*100 + 80 + c8*8] = z;
        if (tid < 128) *(uint4*)&Ks[row*100 + 80 + c8*8] = z;
    }
    // ones-row init for the l-accumulator d-tile: VTs rows 80..95 cols 0..63
    if (tid < 128) {
        int row = 80 + (tid >> 3), c8 = (tid & 7) * 8;
        union { uint4 u; bf16 h8[8]; } z;
        bf16 val = (row == 80) ? f2b(1.0f) : f2b(0.0f);
        #pragma unroll
        for (int u = 0; u < 8; u++) z.h8[u] = val;
        *(uint4*)&VTs[row*68 + c8] = z.u;
    }
    __syncthreads();

    // ---- Q A-frags: 2 m-tiles x 3 ksteps
    bf16x8 qf[2][3];
    #pragma unroll
    for (int m = 0; m < 2; m++)
        #pragma unroll
        for (int ks = 0; ks < 3; ks++)
            qf[m][ks] = *(const bf16x8*)&Qs[(wv*32 + m*16 + l15)*100 + ks*32 + quad*8];

    f32x4 o_acc[2][6] = {};   // [m][dt]; dt=5 col 0 accumulates l
    bf16* PT = (bf16*)(smem + wv * 4352);   // [32][68]

    const bool q_full = (q0 + 128) <= len;

    for (int kt = 0; kt < 16; kt++) {
        __syncthreads();   // prev tile LDS reads done; kt=0: qf loaded (PT/Qs alias safe)
        // stage K tile with fused RoPE: 64 rows x 5 pair-chunks = 320 tasks
        #pragma unroll
        for (int i = 0; i < 2; i++) {
            int c = tid + i * 256;
            if (c < 320) {
                int row = c / 5, pc = c % 5;
                int s = kt*64 + row;
                const bf16* src = k + (size_t)(b*S_ + s)*E_ + h*D_ + pc*8;
                uint4 olo, ohi;
                rope8(src, src + 40, cosp + s*D_ + pc*8, sinp + s*D_ + pc*8, 1.0f, &olo, &ohi);
                *(uint4*)&Ks[row*100 + pc*8]      = olo;
                *(uint4*)&Ks[row*100 + pc*8 + 40] = ohi;
            }
        }
        // stage VT tile (640 chunks): VTs[d][key], rows 0..79 only
        #pragma unroll
        for (int i = 0; i < 3; i++) {
            int c = tid + i * 256;
            if (c < 640) {
                int d = c >> 3, kc = c & 7;
                *(uint4*)&VTs[d*68 + kc*8] =
                    *(const uint4*)(vt + ((size_t)(b*H_ + h)*D_ + d)*S_ + kt*64 + kc*8);
            }
        }
        __syncthreads();

        // ---- QK^T: K-frags shared across the 2 m-tiles
        f32x4 s4[2][4];
        #pragma unroll
        for (int nt = 0; nt < 4; nt++) {
            f32x4 a0 = {}, a1 = {};
            #pragma unroll
            for (int ks = 0; ks < 3; ks++) {
                bf16x8 kf = *(const bf16x8*)&Ks[(nt*16 + l15)*100 + ks*32 + quad*8];
                a0 = __builtin_amdgcn_mfma_f32_16x16x32_bf16(qf[0][ks], kf, a0, 0, 0, 0);
                a1 = __builtin_amdgcn_mfma_f32_16x16x32_bf16(qf[1][ks], kf, a1, 0, 0, 0);
            }
            s4[0][nt] = a0; s4[1][nt] = a1;
        }

        const bool full = q_full && (kt*64 + 64) <= len;
        bool vk[4];
        #pragma unroll
        for (int nt = 0; nt < 4; nt++) vk[nt] = (kt*64 + nt*16 + l15) < len;

        // ---- max-free softmax: p = exp(s); masked -> 0; invalid q-row -> uniform
        #pragma unroll
        for (int m = 0; m < 2; m++) {
            float p[4][4];
            if (full) {
                #pragma unroll
                for (int nt = 0; nt < 4; nt++)
                    #pragma unroll
                    for (int r = 0; r < 4; r++)
                        p[nt][r] = __expf(s4[m][nt][r]);
            } else {
                #pragma unroll
                for (int r = 0; r < 4; r++) {
                    const bool vq = (q0 + wv*32 + m*16 + quad*4 + r) < len;
                    #pragma unroll
                    for (int nt = 0; nt < 4; nt++) {
                        float sv = vq ? (vk[nt] ? s4[m][nt][r] : -1e9f) : 0.0f;
                        p[nt][r] = __expf(sv);
                    }
                }
            }
            // P (C-layout) -> PT (A-layout)
            #pragma unroll
            for (int nt = 0; nt < 4; nt++)
                #pragma unroll
                for (int r = 0; r < 4; r++)
                    PT[(m*16 + quad*4 + r)*68 + nt*16 + l15] = f2b(p[nt][r]);
        }

        // ---- PV: 6 d-tiles (dt=5 = ones-col -> l); V frags shared across m
        bf16x8 pa[2][2];
        #pragma unroll
        for (int m = 0; m < 2; m++)
            #pragma unroll
            for (int ks = 0; ks < 2; ks++)
                pa[m][ks] = *(const bf16x8*)&PT[(m*16 + l15)*68 + ks*32 + quad*8];
        #pragma unroll
        for (int dt = 0; dt < 6; dt++) {
            #pragma unroll
            for (int ks = 0; ks < 2; ks++) {
                bf16x8 vf = *(const bf16x8*)&VTs[(dt*16 + l15)*68 + ks*32 + quad*8];
                o_acc[0][dt] = __builtin_amdgcn_mfma_f32_16x16x32_bf16(pa[0][ks], vf, o_acc[0][dt], 0, 0, 0);
                o_acc[1][dt] = __builtin_amdgcn_mfma_f32_16x16x32_bf16(pa[1][ks], vf, o_acc[1][dt], 0, 0, 0);
            }
        }
    }

    // ---- epilogue: l = o_acc[5] col 0 (lane l15==0 of each quad group)
    #pragma unroll
    for (int m = 0; m < 2; m++)
        #pragma unroll
        for (int r = 0; r < 4; r++) {
            float l = __shfl(o_acc[m][5][r], lane & 48, 64);  // broadcast col-0 lane
            const float inv = 1.0f / l;
            size_t row_g = (size_t)(b*S_ + q0 + wv*32 + m*16 + quad*4 + r);
            #pragma unroll
            for (int dt = 0; dt < 5; dt++)
                o[row_g*E_ + h*D_ + dt*16 + l15] = f2b(o_acc[m][dt][r] * inv);
        }
}

extern "C" void kernel_launch(void* const* d_in, const int* in_sizes, int n_in,
                              void* d_out, int out_size, void* d_ws, size_t ws_size,
                              hipStream_t stream)
{
    const float* x    = (const float*)d_in[0];
    const int*   cu   = (const int*)  d_in[1];
    const float* cosp = (const float*)d_in[2];
    const float* sinp = (const float*)d_in[3];
    const float* wq   = (const float*)d_in[4];
    const float* bq   = (const float*)d_in[5];
    const float* wk   = (const float*)d_in[6];
    const float* bk   = (const float*)d_in[7];
    const float* wv   = (const float*)d_in[8];
    const float* bv   = (const float*)d_in[9];
    const float* wo   = (const float*)d_in[10];
    const float* bo   = (const float*)d_in[11];
    float* out = (float*)d_out;

    bf16* q   = (bf16*)d_ws;
    bf16* kk  = q   + (size_t)M_ * E_;
    bf16* vt  = kk  + (size_t)M_ * E_;   // transposed V: [B][H][D][S]
    bf16* ao  = vt  + (size_t)M_ * E_;
    bf16* xb  = ao  + (size_t)M_ * E_;
    bf16* wqb = xb  + (size_t)M_ * E_;
    bf16* wkb = wqb + (size_t)E_ * E_;
    bf16* wvb = wkb + (size_t)E_ * E_;
    bf16* wob = wvb + (size_t)E_ * E_;

    // 0) convert x + 4 weight matrices to bf16
    cvt_kernel<<<dim3(2560, 5), 256, 0, stream>>>(
        x, wq, wk, wv, wo, xb, wqb, wkb, wvb, wob, M_*E_, E_*E_);

    // 1) QKV projection (MFMA), bias fused; V written transposed.
    //    q/k hold PRE-rope values (rope fused into attention staging).
    mfma_gemm_bt<bf16, true><<<dim3(M_/128, 30), 256, 0, stream>>>(
        xb, wqb, wkb, wvb, bq, bk, bv, q, kk, vt, E_, E_, 10);

    // 2) MFMA flash attention (max-free softmax, XCD-swizzled, fused RoPE)
    attn_mfma<<<512, 256, 0, stream>>>(q, kk, vt, cu, cosp, sinp, ao);

    // 3) output projection (MFMA), fp32 out, bias fused
    mfma_gemm_bt<float, false><<<dim3(M_/128, 10), 256, 0, stream>>>(
        ao, wob, wob, wob, bo, bo, bo, out, out, out, E_, E_, 10);
}

// Round 10
// 281.946 us; speedup vs baseline: 1.2775x; 1.2095x over previous
//
#include <hip/hip_runtime.h>
#include <hip/hip_bf16.h>

#define B_ 4
#define S_ 1024
#define E_ 1280
#define H_ 16
#define D_ 80
#define M_ (B_*S_)   // 4096

typedef __hip_bfloat16 bf16;
using bf16x8 = __attribute__((ext_vector_type(8))) short;  // 8 bf16 = 4 VGPRs
using f32x4  = __attribute__((ext_vector_type(4))) float;  // MFMA C/D frag

__device__ __forceinline__ float b2f(bf16 x){ return __bfloat162float(x); }
__device__ __forceinline__ bf16  f2b(float x){ return __float2bfloat16(x); }
__device__ __forceinline__ void  stf(float* p, float v){ *p = v; }
__device__ __forceinline__ void  stf(bf16*  p, float v){ *p = f2b(v); }

__device__ __forceinline__ void gload_lds16(const void* g, void* l) {
    __builtin_amdgcn_global_load_lds(
        (const __attribute__((address_space(1))) unsigned int*)g,
        (__attribute__((address_space(3))) unsigned int*)l, 16, 0, 0);
}

// fp32 -> bf16 conversion, 8 elems/thread. blockIdx.y selects segment.
__global__ __launch_bounds__(256) void cvt_kernel(
    const float* __restrict__ s0, const float* __restrict__ s1,
    const float* __restrict__ s2, const float* __restrict__ s3,
    const float* __restrict__ s4,
    bf16* __restrict__ d0, bf16* __restrict__ d1, bf16* __restrict__ d2,
    bf16* __restrict__ d3, bf16* __restrict__ d4,
    int n0, int n1)
{
    const float* s; bf16* d; int n;
    switch (blockIdx.y) {
        case 0: s = s0; d = d0; n = n0; break;
        case 1: s = s1; d = d1; n = n1; break;
        case 2: s = s2; d = d2; n = n1; break;
        case 3: s = s3; d = d3; n = n1; break;
        default: s = s4; d = d4; n = n1; break;
    }
    int i = (blockIdx.x * 256 + threadIdx.x) * 8;
    if (i >= n) return;
    float4 a = *(const float4*)(s + i);
    float4 b = *(const float4*)(s + i + 4);
    bf16 t[8];
    t[0]=f2b(a.x); t[1]=f2b(a.y); t[2]=f2b(a.z); t[3]=f2b(a.w);
    t[4]=f2b(b.x); t[5]=f2b(b.y); t[6]=f2b(b.z); t[7]=f2b(b.w);
    *(uint4*)(d + i) = *(const uint4*)t;
}

// m97-style MFMA GEMM, BK=64 (two [128][32] LDS panels per operand).
// C[m,n] = sum_k A[m,k]*W[n,k] + bias[n]
// VT_OUT: mat==2 (V) stores transposed as VT[btok][h][d][key].
template<typename TC, bool VT_OUT>
__global__ __launch_bounds__(256) void mfma_gemm_bt(
    const bf16* __restrict__ A,
    const bf16* __restrict__ W0, const bf16* __restrict__ W1, const bf16* __restrict__ W2,
    const float* __restrict__ b0, const float* __restrict__ b1, const float* __restrict__ b2,
    TC* __restrict__ C0, TC* __restrict__ C1, TC* __restrict__ C2,
    int K, int N, int ntiles)
{
    const int mat = blockIdx.y / ntiles;
    const int bn  = (blockIdx.y % ntiles) * 128;
    const int bm  = blockIdx.x * 128;
    const bf16* W; const float* bias; TC* C;
    if (mat == 0)      { W = W0; bias = b0; C = C0; }
    else if (mat == 1) { W = W1; bias = b1; C = C1; }
    else               { W = W2; bias = b2; C = C2; }

    __shared__ bf16 As[2][128][32];   // panel p covers k0 + p*32 .. +32
    __shared__ bf16 Ws[2][128][32];

    const int tid  = threadIdx.x;
    const int lane = tid & 63;
    const int wv   = tid >> 6;
    const int wm   = (wv & 1) * 64;
    const int wn   = (wv >> 1) * 64;
    const int srow = wv * 16 + (lane >> 2);
    const int scol = (lane & 3) * 8;

    f32x4 acc[4][4] = {};

    for (int k0 = 0; k0 < K; k0 += 64) {
        __syncthreads();
        #pragma unroll
        for (int p = 0; p < 2; p++) {
            const int kc = k0 + p*32 + scol;
            gload_lds16(A + (size_t)(bm + srow)      * K + kc, &As[p][wv*16][0]);
            gload_lds16(A + (size_t)(bm + 64 + srow) * K + kc, &As[p][64 + wv*16][0]);
            gload_lds16(W + (size_t)(bn + srow)      * K + kc, &Ws[p][wv*16][0]);
            gload_lds16(W + (size_t)(bn + 64 + srow) * K + kc, &Ws[p][64 + wv*16][0]);
        }
        __syncthreads();

        const int fr = lane & 15;
        const int kq = (lane >> 4) * 8;
        #pragma unroll
        for (int p = 0; p < 2; p++) {
            bf16x8 af[4], wf[4];
            #pragma unroll
            for (int t = 0; t < 4; t++) {
                af[t] = *(const bf16x8*)&As[p][wm + t*16 + fr][kq];
                wf[t] = *(const bf16x8*)&Ws[p][wn + t*16 + fr][kq];
            }
            #pragma unroll
            for (int mt = 0; mt < 4; mt++)
                #pragma unroll
                for (int nt = 0; nt < 4; nt++)
                    acc[mt][nt] = __builtin_amdgcn_mfma_f32_16x16x32_bf16(
                        af[mt], wf[nt], acc[mt][nt], 0, 0, 0);
        }
    }

    const int col_l = lane & 15;
    const int row_l = (lane >> 4) * 4;

    if (VT_OUT && mat == 2) {
        const int btok = bm >> 10;
        const int keyb = (bm & 1023) + wm + row_l;
        #pragma unroll
        for (int nt = 0; nt < 4; nt++) {
            const int n = bn + wn + nt*16 + col_l;
            const float bv = bias[n];
            const int hh = n / 80, dd = n % 80;
            bf16* vbase = (bf16*)C + ((size_t)(btok*H_ + hh)*D_ + dd)*S_ + keyb;
            #pragma unroll
            for (int mt = 0; mt < 4; mt++) {
                union { bf16 h[4]; uint2 u; } t4;
                #pragma unroll
                for (int r = 0; r < 4; r++) t4.h[r] = f2b(acc[mt][nt][r] + bv);
                *(uint2*)&vbase[mt*16] = t4.u;
            }
        }
    } else {
        #pragma unroll
        for (int nt = 0; nt < 4; nt++) {
            const int n = bn + wn + nt*16 + col_l;
            const float bv = bias[n];
            #pragma unroll
            for (int mt = 0; mt < 4; mt++) {
                #pragma unroll
                for (int r = 0; r < 4; r++) {
                    const int m = bm + wm + mt*16 + row_l + r;
                    stf(&C[(size_t)m * N + n], acc[mt][nt][r] + bv);
                }
            }
        }
    }
}

// rope helper: lo=dims j..j+8 (j<40), hi=j+40.. ; out_lo = x1*c - x2*s, out_hi = x2*c + x1*s
__device__ __forceinline__ void rope8(const bf16* lo, const bf16* hi,
                                      const float* cp, const float* sp,
                                      float mul, uint4* out_lo, uint4* out_hi)
{
    union { uint4 u; bf16 h[8]; } li, hi_, lo_o, hi_o;
    li.u  = *(const uint4*)lo;
    hi_.u = *(const uint4*)hi;
    #pragma unroll
    for (int u = 0; u < 8; u++) {
        float x1 = b2f(li.h[u]), x2 = b2f(hi_.h[u]);
        float c = cp[u], s = sp[u];
        lo_o.h[u] = f2b((x1*c - x2*s) * mul);
        hi_o.h[u] = f2b((x2*c + x1*s) * mul);
    }
    *out_lo = lo_o.u;
    *out_hi = hi_o.u;
}

// MFMA flash attention (R7 configuration — best measured: 95 us).
// 1-D grid, XCD-swizzled: L = g + 64*qt. Online softmax in registers,
// RoPE fused into staging, V pre-transposed (VT[b][h][d][key]).
__global__ __launch_bounds__(256, 2) void attn_mfma(
    const bf16* __restrict__ q, const bf16* __restrict__ k, const bf16* __restrict__ vt,
    const int* __restrict__ cu, const float* __restrict__ cosp, const float* __restrict__ sinp,
    bf16* __restrict__ o)
{
    // Qs[128][104] @0 (26624 B) | Ks[64][104] @26624 (13312 B) | VTs[80][72] @39936 (11520 B)
    // PT per-wave [32][72] (4608 B) aliases Qs (Q frags in regs before first PT write).
    __shared__ __align__(16) char smem[51456];
    bf16* Qs  = (bf16*)smem;
    bf16* Ks  = (bf16*)(smem + 26624);
    bf16* VTs = (bf16*)(smem + 39936);

    const int L  = blockIdx.x;
    const int qt = L >> 6;
    const int g  = L & 63;
    const int b  = g >> 4;
    const int h  = g & 15;

    const int tid = threadIdx.x;
    const int lane = tid & 63, wv = tid >> 6;
    const int quad = lane >> 4, l15 = lane & 15;
    const int q0 = qt * 128;
    const int len = cu[b + 1] - cu[b];
    const float scale = 0.11180339887498949f;  // 1/sqrt(80), folded into Q

    // ---- stage Q with fused RoPE (pre-scaled): 128 rows x 5 pair-chunks = 640 tasks
    #pragma unroll
    for (int i = 0; i < 3; i++) {
        int c = tid + i * 256;
        if (c < 640) {
            int row = c / 5, pc = c % 5;
            int s = q0 + row;
            const bf16* src = q + (size_t)(b*S_ + s)*E_ + h*D_ + pc*8;
            uint4 olo, ohi;
            rope8(src, src + 40, cosp + s*D_ + pc*8, sinp + s*D_ + pc*8, scale, &olo, &ohi);
            *(uint4*)&Qs[row*104 + pc*8]      = olo;
            *(uint4*)&Qs[row*104 + (pc+5)*8]  = ohi;
        }
    }
    // zero-pad cols 80..95 (Qs: 256 chunks, Ks: 128 chunks)
    {
        uint4 z = make_uint4(0,0,0,0);
        int row = tid >> 1, c8 = 10 + (tid & 1);
        *(uint4*)&Qs[row*104 + c8*8] = z;
        if (tid < 128) *(uint4*)&Ks[row*104 + c8*8] = z;
    }
    __syncthreads();

    // ---- Q A-frags: 2 m-tiles x 3 ksteps
    bf16x8 qf[2][3];
    #pragma unroll
    for (int m = 0; m < 2; m++)
        #pragma unroll
        for (int ks = 0; ks < 3; ks++)
            qf[m][ks] = *(const bf16x8*)&Qs[(wv*32 + m*16 + l15)*104 + ks*32 + quad*8];

    float m_r[2][4], l_r[2][4];
    #pragma unroll
    for (int m = 0; m < 2; m++)
        #pragma unroll
        for (int r = 0; r < 4; r++) { m_r[m][r] = -1e30f; l_r[m][r] = 0.f; }
    f32x4 o_acc[2][5] = {};
    bf16* PT = (bf16*)(smem + wv * 4608);   // [32][72]

    const bool q_full = (q0 + 128) <= len;

    for (int kt = 0; kt < 16; kt++) {
        __syncthreads();   // prev tile LDS reads done; kt=0: qf loaded (PT/Qs alias safe)
        // stage K tile with fused RoPE: 64 rows x 5 pair-chunks = 320 tasks
        #pragma unroll
        for (int i = 0; i < 2; i++) {
            int c = tid + i * 256;
            if (c < 320) {
                int row = c / 5, pc = c % 5;
                int s = kt*64 + row;
                const bf16* src = k + (size_t)(b*S_ + s)*E_ + h*D_ + pc*8;
                uint4 olo, ohi;
                rope8(src, src + 40, cosp + s*D_ + pc*8, sinp + s*D_ + pc*8, 1.0f, &olo, &ohi);
                *(uint4*)&Ks[row*104 + pc*8]      = olo;
                *(uint4*)&Ks[row*104 + (pc+5)*8]  = ohi;
            }
        }
        // stage VT tile (640 chunks): VTs[d][key]
        #pragma unroll
        for (int i = 0; i < 3; i++) {
            int c = tid + i * 256;
            if (c < 640) {
                int d = c >> 3, kc = c & 7;
                *(uint4*)&VTs[d*72 + kc*8] =
                    *(const uint4*)(vt + ((size_t)(b*H_ + h)*D_ + d)*S_ + kt*64 + kc*8);
            }
        }
        __syncthreads();

        // ---- QK^T: K-frags shared across the 2 m-tiles
        f32x4 s4[2][4];
        #pragma unroll
        for (int nt = 0; nt < 4; nt++) {
            f32x4 a0 = {}, a1 = {};
            #pragma unroll
            for (int ks = 0; ks < 3; ks++) {
                bf16x8 kf = *(const bf16x8*)&Ks[(nt*16 + l15)*104 + ks*32 + quad*8];
                a0 = __builtin_amdgcn_mfma_f32_16x16x32_bf16(qf[0][ks], kf, a0, 0, 0, 0);
                a1 = __builtin_amdgcn_mfma_f32_16x16x32_bf16(qf[1][ks], kf, a1, 0, 0, 0);
            }
            s4[0][nt] = a0; s4[1][nt] = a1;
        }

        const bool full = q_full && (kt*64 + 64) <= len;
        bool vk[4];
        #pragma unroll
        for (int nt = 0; nt < 4; nt++) vk[nt] = (kt*64 + nt*16 + l15) < len;

        // ---- online softmax per m-tile (rows quad*4+r, wave-exclusive)
        #pragma unroll
        for (int m = 0; m < 2; m++) {
            float sv[4][4];
            if (full) {
                #pragma unroll
                for (int r = 0; r < 4; r++)
                    #pragma unroll
                    for (int nt = 0; nt < 4; nt++)
                        sv[nt][r] = s4[m][nt][r];
            } else {
                #pragma unroll
                for (int r = 0; r < 4; r++) {
                    const bool vq = (q0 + wv*32 + m*16 + quad*4 + r) < len;
                    #pragma unroll
                    for (int nt = 0; nt < 4; nt++)
                        sv[nt][r] = (vq && vk[nt]) ? s4[m][nt][r] : -1e9f;
                }
            }
            float rmax[4];
            #pragma unroll
            for (int r = 0; r < 4; r++)
                rmax[r] = fmaxf(fmaxf(sv[0][r], sv[1][r]), fmaxf(sv[2][r], sv[3][r]));
            #pragma unroll
            for (int st = 1; st < 16; st <<= 1)
                #pragma unroll
                for (int r = 0; r < 4; r++)
                    rmax[r] = fmaxf(rmax[r], __shfl_xor(rmax[r], st, 64));
            float mnew[4], alpha[4], rsum[4], p[4][4];
            #pragma unroll
            for (int r = 0; r < 4; r++) {
                mnew[r]  = fmaxf(m_r[m][r], rmax[r]);
                alpha[r] = __expf(m_r[m][r] - mnew[r]);
                float a = 0.f;
                #pragma unroll
                for (int nt = 0; nt < 4; nt++) { p[nt][r] = __expf(sv[nt][r] - mnew[r]); a += p[nt][r]; }
                rsum[r] = a;
            }
            #pragma unroll
            for (int st = 1; st < 16; st <<= 1)
                #pragma unroll
                for (int r = 0; r < 4; r++)
                    rsum[r] += __shfl_xor(rsum[r], st, 64);
            #pragma unroll
            for (int r = 0; r < 4; r++) {
                l_r[m][r] = l_r[m][r] * alpha[r] + rsum[r];
                m_r[m][r] = mnew[r];
            }
            #pragma unroll
            for (int dt = 0; dt < 5; dt++)
                #pragma unroll
                for (int r = 0; r < 4; r++)
                    o_acc[m][dt][r] *= alpha[r];
            // P (C-layout) -> PT (A-layout)
            #pragma unroll
            for (int nt = 0; nt < 4; nt++)
                #pragma unroll
                for (int r = 0; r < 4; r++)
                    PT[(m*16 + quad*4 + r)*72 + nt*16 + l15] = f2b(p[nt][r]);
        }

        // ---- PV: V B-frags b128 from VTs, shared across m-tiles
        bf16x8 pa[2][2];
        #pragma unroll
        for (int m = 0; m < 2; m++)
            #pragma unroll
            for (int ks = 0; ks < 2; ks++)
                pa[m][ks] = *(const bf16x8*)&PT[(m*16 + l15)*72 + ks*32 + quad*8];
        #pragma unroll
        for (int dt = 0; dt < 5; dt++) {
            #pragma unroll
            for (int ks = 0; ks < 2; ks++) {
                bf16x8 vf = *(const bf16x8*)&VTs[(dt*16 + l15)*72 + ks*32 + quad*8];
                o_acc[0][dt] = __builtin_amdgcn_mfma_f32_16x16x32_bf16(pa[0][ks], vf, o_acc[0][dt], 0, 0, 0);
                o_acc[1][dt] = __builtin_amdgcn_mfma_f32_16x16x32_bf16(pa[1][ks], vf, o_acc[1][dt], 0, 0, 0);
            }
        }
    }

    // ---- epilogue
    #pragma unroll
    for (int m = 0; m < 2; m++)
        #pragma unroll
        for (int r = 0; r < 4; r++) {
            const float inv = 1.0f / l_r[m][r];
            size_t row_g = (size_t)(b*S_ + q0 + wv*32 + m*16 + quad*4 + r);
            #pragma unroll
            for (int dt = 0; dt < 5; dt++)
                o[row_g*E_ + h*D_ + dt*16 + l15] = f2b(o_acc[m][dt][r] * inv);
        }
}

extern "C" void kernel_launch(void* const* d_in, const int* in_sizes, int n_in,
                              void* d_out, int out_size, void* d_ws, size_t ws_size,
                              hipStream_t stream)
{
    const float* x    = (const float*)d_in[0];
    const int*   cu   = (const int*)  d_in[1];
    const float* cosp = (const float*)d_in[2];
    const float* sinp = (const float*)d_in[3];
    const float* wq   = (const float*)d_in[4];
    const float* bq   = (const float*)d_in[5];
    const float* wk   = (const float*)d_in[6];
    const float* bk   = (const float*)d_in[7];
    const float* wv   = (const float*)d_in[8];
    const float* bv   = (const float*)d_in[9];
    const float* wo   = (const float*)d_in[10];
    const float* bo   = (const float*)d_in[11];
    float* out = (float*)d_out;

    bf16* q   = (bf16*)d_ws;
    bf16* kk  = q   + (size_t)M_ * E_;
    bf16* vt  = kk  + (size_t)M_ * E_;   // transposed V: [B][H][D][S]
    bf16* ao  = vt  + (size_t)M_ * E_;
    bf16* xb  = ao  + (size_t)M_ * E_;
    bf16* wqb = xb  + (size_t)M_ * E_;
    bf16* wkb = wqb + (size_t)E_ * E_;
    bf16* wvb = wkb + (size_t)E_ * E_;
    bf16* wob = wvb + (size_t)E_ * E_;

    // 0) convert x + 4 weight matrices to bf16
    cvt_kernel<<<dim3(2560, 5), 256, 0, stream>>>(
        x, wq, wk, wv, wo, xb, wqb, wkb, wvb, wob, M_*E_, E_*E_);

    // 1) QKV projection (MFMA, BK=64), bias fused; V written transposed.
    //    q/k hold PRE-rope values (rope fused into attention staging).
    mfma_gemm_bt<bf16, true><<<dim3(M_/128, 30), 256, 0, stream>>>(
        xb, wqb, wkb, wvb, bq, bk, bv, q, kk, vt, E_, E_, 10);

    // 2) MFMA flash attention (R7 config: online softmax, XCD swizzle, fused RoPE)
    attn_mfma<<<512, 256, 0, stream>>>(q, kk, vt, cu, cosp, sinp, ao);

    // 3) output projection (MFMA, BK=64), fp32 out, bias fused
    mfma_gemm_bt<float, false><<<dim3(M_/128, 10), 256, 0, stream>>>(
        ao, wob, wob, wob, bo, bo, bo, out, out, out, E_, E_, 10);
}

// Round 11
// 274.290 us; speedup vs baseline: 1.3131x; 1.0279x over previous
//
#include <hip/hip_runtime.h>
#include <hip/hip_bf16.h>

#define B_ 4
#define S_ 1024
#define E_ 1280
#define H_ 16
#define D_ 80
#define M_ (B_*S_)   // 4096

typedef __hip_bfloat16 bf16;
using bf16x8 = __attribute__((ext_vector_type(8))) short;  // 8 bf16 = 4 VGPRs
using f32x4  = __attribute__((ext_vector_type(4))) float;  // MFMA C/D frag

__device__ __forceinline__ float b2f(bf16 x){ return __bfloat162float(x); }
__device__ __forceinline__ bf16  f2b(float x){ return __float2bfloat16(x); }
__device__ __forceinline__ void  stf(float* p, float v){ *p = v; }
__device__ __forceinline__ void  stf(bf16*  p, float v){ *p = f2b(v); }

__device__ __forceinline__ void gload_lds16(const void* g, void* l) {
    __builtin_amdgcn_global_load_lds(
        (const __attribute__((address_space(1))) unsigned int*)g,
        (__attribute__((address_space(3))) unsigned int*)l, 16, 0, 0);
}

// fp32 -> bf16 conversion, 8 elems/thread. blockIdx.y selects segment.
__global__ __launch_bounds__(256) void cvt_kernel(
    const float* __restrict__ s0, const float* __restrict__ s1,
    const float* __restrict__ s2, const float* __restrict__ s3,
    const float* __restrict__ s4,
    bf16* __restrict__ d0, bf16* __restrict__ d1, bf16* __restrict__ d2,
    bf16* __restrict__ d3, bf16* __restrict__ d4,
    int n0, int n1)
{
    const float* s; bf16* d; int n;
    switch (blockIdx.y) {
        case 0: s = s0; d = d0; n = n0; break;
        case 1: s = s1; d = d1; n = n1; break;
        case 2: s = s2; d = d2; n = n1; break;
        case 3: s = s3; d = d3; n = n1; break;
        default: s = s4; d = d4; n = n1; break;
    }
    int i = (blockIdx.x * 256 + threadIdx.x) * 8;
    if (i >= n) return;
    float4 a = *(const float4*)(s + i);
    float4 b = *(const float4*)(s + i + 4);
    bf16 t[8];
    t[0]=f2b(a.x); t[1]=f2b(a.y); t[2]=f2b(a.z); t[3]=f2b(a.w);
    t[4]=f2b(b.x); t[5]=f2b(b.y); t[6]=f2b(b.z); t[7]=f2b(b.w);
    *(uint4*)(d + i) = *(const uint4*)t;
}

// m97-style MFMA GEMM, BK=64 (two [128][32] LDS panels per operand).
// C[m,n] = sum_k A[m,k]*W[n,k] + bias[n]
// VT_OUT: mat==2 (V) stores transposed as VT[btok][h][d][key].
template<typename TC, bool VT_OUT>
__global__ __launch_bounds__(256) void mfma_gemm_bt(
    const bf16* __restrict__ A,
    const bf16* __restrict__ W0, const bf16* __restrict__ W1, const bf16* __restrict__ W2,
    const float* __restrict__ b0, const float* __restrict__ b1, const float* __restrict__ b2,
    TC* __restrict__ C0, TC* __restrict__ C1, TC* __restrict__ C2,
    int K, int N, int ntiles)
{
    const int mat = blockIdx.y / ntiles;
    const int bn  = (blockIdx.y % ntiles) * 128;
    const int bm  = blockIdx.x * 128;
    const bf16* W; const float* bias; TC* C;
    if (mat == 0)      { W = W0; bias = b0; C = C0; }
    else if (mat == 1) { W = W1; bias = b1; C = C1; }
    else               { W = W2; bias = b2; C = C2; }

    __shared__ bf16 As[2][128][32];   // panel p covers k0 + p*32 .. +32
    __shared__ bf16 Ws[2][128][32];

    const int tid  = threadIdx.x;
    const int lane = tid & 63;
    const int wv   = tid >> 6;
    const int wm   = (wv & 1) * 64;
    const int wn   = (wv >> 1) * 64;
    const int srow = wv * 16 + (lane >> 2);
    const int scol = (lane & 3) * 8;

    f32x4 acc[4][4] = {};

    for (int k0 = 0; k0 < K; k0 += 64) {
        __syncthreads();
        #pragma unroll
        for (int p = 0; p < 2; p++) {
            const int kc = k0 + p*32 + scol;
            gload_lds16(A + (size_t)(bm + srow)      * K + kc, &As[p][wv*16][0]);
            gload_lds16(A + (size_t)(bm + 64 + srow) * K + kc, &As[p][64 + wv*16][0]);
            gload_lds16(W + (size_t)(bn + srow)      * K + kc, &Ws[p][wv*16][0]);
            gload_lds16(W + (size_t)(bn + 64 + srow) * K + kc, &Ws[p][64 + wv*16][0]);
        }
        __syncthreads();

        const int fr = lane & 15;
        const int kq = (lane >> 4) * 8;
        #pragma unroll
        for (int p = 0; p < 2; p++) {
            bf16x8 af[4], wf[4];
            #pragma unroll
            for (int t = 0; t < 4; t++) {
                af[t] = *(const bf16x8*)&As[p][wm + t*16 + fr][kq];
                wf[t] = *(const bf16x8*)&Ws[p][wn + t*16 + fr][kq];
            }
            #pragma unroll
            for (int mt = 0; mt < 4; mt++)
                #pragma unroll
                for (int nt = 0; nt < 4; nt++)
                    acc[mt][nt] = __builtin_amdgcn_mfma_f32_16x16x32_bf16(
                        af[mt], wf[nt], acc[mt][nt], 0, 0, 0);
        }
    }

    const int col_l = lane & 15;
    const int row_l = (lane >> 4) * 4;

    if (VT_OUT && mat == 2) {
        const int btok = bm >> 10;
        const int keyb = (bm & 1023) + wm + row_l;
        #pragma unroll
        for (int nt = 0; nt < 4; nt++) {
            const int n = bn + wn + nt*16 + col_l;
            const float bv = bias[n];
            const int hh = n / 80, dd = n % 80;
            bf16* vbase = (bf16*)C + ((size_t)(btok*H_ + hh)*D_ + dd)*S_ + keyb;
            #pragma unroll
            for (int mt = 0; mt < 4; mt++) {
                union { bf16 h[4]; uint2 u; } t4;
                #pragma unroll
                for (int r = 0; r < 4; r++) t4.h[r] = f2b(acc[mt][nt][r] + bv);
                *(uint2*)&vbase[mt*16] = t4.u;
            }
        }
    } else {
        #pragma unroll
        for (int nt = 0; nt < 4; nt++) {
            const int n = bn + wn + nt*16 + col_l;
            const float bv = bias[n];
            #pragma unroll
            for (int mt = 0; mt < 4; mt++) {
                #pragma unroll
                for (int r = 0; r < 4; r++) {
                    const int m = bm + wm + mt*16 + row_l + r;
                    stf(&C[(size_t)m * N + n], acc[mt][nt][r] + bv);
                }
            }
        }
    }
}

// rope helper: lo=dims j..j+8 (j<40), hi=j+40.. ; out_lo = x1*c - x2*s, out_hi = x2*c + x1*s
__device__ __forceinline__ void rope8(const bf16* lo, const bf16* hi,
                                      const float* cp, const float* sp,
                                      float mul, uint4* out_lo, uint4* out_hi)
{
    union { uint4 u; bf16 h[8]; } li, hi_, lo_o, hi_o;
    li.u  = *(const uint4*)lo;
    hi_.u = *(const uint4*)hi;
    #pragma unroll
    for (int u = 0; u < 8; u++) {
        float x1 = b2f(li.h[u]), x2 = b2f(hi_.h[u]);
        float c = cp[u], s = sp[u];
        lo_o.h[u] = f2b((x1*c - x2*s) * mul);
        hi_o.h[u] = f2b((x2*c + x1*s) * mul);
    }
    *out_lo = lo_o.u;
    *out_hi = hi_o.u;
}

// MFMA flash attention v6 — R7 refinements at 4 blocks/CU.
// 64-row q-tiles -> grid 1024 (4 blocks/CU), LDS 38144 B.
// 1-D grid, XCD-swizzled: L = g + 64*qt (all 16 q-tiles of a (b,h) share L%8).
// Online softmax in registers (wave owns 16 q-rows), RoPE fused into staging,
// V pre-transposed (VT[b][h][d][key]) -> b128 B-frag reads.
__global__ __launch_bounds__(256, 4) void attn_mfma(
    const bf16* __restrict__ q, const bf16* __restrict__ k, const bf16* __restrict__ vt,
    const int* __restrict__ cu, const float* __restrict__ cosp, const float* __restrict__ sinp,
    bf16* __restrict__ o)
{
    // Qs[64][104] @0 (13312 B) | Ks[64][104] @13312 | VTs[80][72] @26624 (11520 B)
    // PT per-wave [16][72] (2304 B) aliases Qs (all qf in regs + barrier before first PT write).
    __shared__ __align__(16) char smem[38144];
    bf16* Qs  = (bf16*)smem;
    bf16* Ks  = (bf16*)(smem + 13312);
    bf16* VTs = (bf16*)(smem + 26624);

    const int L  = blockIdx.x;
    const int qt = L >> 6;          // 0..15
    const int g  = L & 63;
    const int b  = g >> 4;
    const int h  = g & 15;

    const int tid = threadIdx.x;
    const int lane = tid & 63, wv = tid >> 6;
    const int quad = lane >> 4, l15 = lane & 15;
    const int q0 = qt * 64;
    const int len = cu[b + 1] - cu[b];
    const float scale = 0.11180339887498949f;  // 1/sqrt(80), folded into Q

    // ---- stage Q with fused RoPE (pre-scaled): 64 rows x 5 pair-chunks = 320 tasks
    #pragma unroll
    for (int i = 0; i < 2; i++) {
        int c = tid + i * 256;
        if (c < 320) {
            int row = c / 5, pc = c % 5;
            int s = q0 + row;
            const bf16* src = q + (size_t)(b*S_ + s)*E_ + h*D_ + pc*8;
            uint4 olo, ohi;
            rope8(src, src + 40, cosp + s*D_ + pc*8, sinp + s*D_ + pc*8, scale, &olo, &ohi);
            *(uint4*)&Qs[row*104 + pc*8]      = olo;
            *(uint4*)&Qs[row*104 + (pc+5)*8]  = ohi;
        }
    }
    // zero-pad cols 80..95 (Qs: 128 chunks, Ks: 128 chunks)
    if (tid < 128) {
        uint4 z = make_uint4(0,0,0,0);
        int row = tid >> 1, c8 = 10 + (tid & 1);
        *(uint4*)&Qs[row*104 + c8*8] = z;
        *(uint4*)&Ks[row*104 + c8*8] = z;
    }
    __syncthreads();

    // ---- Q A-frags: 1 m-tile (wave owns rows wv*16..+16) x 3 ksteps
    bf16x8 qf[3];
    #pragma unroll
    for (int ks = 0; ks < 3; ks++)
        qf[ks] = *(const bf16x8*)&Qs[(wv*16 + l15)*104 + ks*32 + quad*8];

    float m_r[4], l_r[4];
    #pragma unroll
    for (int r = 0; r < 4; r++) { m_r[r] = -1e30f; l_r[r] = 0.f; }
    f32x4 o_acc[5] = {};
    bf16* PT = (bf16*)(smem + wv * 2304);   // [16][72], aliases Qs

    const bool q_full = (q0 + 64) <= len;

    for (int kt = 0; kt < 16; kt++) {
        __syncthreads();   // prev tile LDS reads done; kt=0: all qf loaded (PT/Qs alias safe)
        // stage K tile with fused RoPE: 64 rows x 5 pair-chunks = 320 tasks
        #pragma unroll
        for (int i = 0; i < 2; i++) {
            int c = tid + i * 256;
            if (c < 320) {
                int row = c / 5, pc = c % 5;
                int s = kt*64 + row;
                const bf16* src = k + (size_t)(b*S_ + s)*E_ + h*D_ + pc*8;
                uint4 olo, ohi;
                rope8(src, src + 40, cosp + s*D_ + pc*8, sinp + s*D_ + pc*8, 1.0f, &olo, &ohi);
                *(uint4*)&Ks[row*104 + pc*8]      = olo;
                *(uint4*)&Ks[row*104 + (pc+5)*8]  = ohi;
            }
        }
        // stage VT tile (640 chunks): VTs[d][key]
        #pragma unroll
        for (int i = 0; i < 3; i++) {
            int c = tid + i * 256;
            if (c < 640) {
                int d = c >> 3, kc = c & 7;
                *(uint4*)&VTs[d*72 + kc*8] =
                    *(const uint4*)(vt + ((size_t)(b*H_ + h)*D_ + d)*S_ + kt*64 + kc*8);
            }
        }
        __syncthreads();

        // ---- QK^T: 4 n-tiles x 3 ksteps
        f32x4 s4[4];
        #pragma unroll
        for (int nt = 0; nt < 4; nt++) {
            f32x4 a0 = {};
            #pragma unroll
            for (int ks = 0; ks < 3; ks++) {
                bf16x8 kf = *(const bf16x8*)&Ks[(nt*16 + l15)*104 + ks*32 + quad*8];
                a0 = __builtin_amdgcn_mfma_f32_16x16x32_bf16(qf[ks], kf, a0, 0, 0, 0);
            }
            s4[nt] = a0;
        }

        const bool full = q_full && (kt*64 + 64) <= len;

        // ---- online softmax (rows quad*4+r, wave-exclusive)
        float sv[4][4];
        if (full) {
            #pragma unroll
            for (int r = 0; r < 4; r++)
                #pragma unroll
                for (int nt = 0; nt < 4; nt++)
                    sv[nt][r] = s4[nt][r];
        } else {
            bool vk[4];
            #pragma unroll
            for (int nt = 0; nt < 4; nt++) vk[nt] = (kt*64 + nt*16 + l15) < len;
            #pragma unroll
            for (int r = 0; r < 4; r++) {
                const bool vq = (q0 + wv*16 + quad*4 + r) < len;
                #pragma unroll
                for (int nt = 0; nt < 4; nt++)
                    sv[nt][r] = (vq && vk[nt]) ? s4[nt][r] : -1e9f;
            }
        }
        float rmax[4];
        #pragma unroll
        for (int r = 0; r < 4; r++)
            rmax[r] = fmaxf(fmaxf(sv[0][r], sv[1][r]), fmaxf(sv[2][r], sv[3][r]));
        #pragma unroll
        for (int st = 1; st < 16; st <<= 1)
            #pragma unroll
            for (int r = 0; r < 4; r++)
                rmax[r] = fmaxf(rmax[r], __shfl_xor(rmax[r], st, 64));
        float mnew[4], alpha[4], rsum[4], p[4][4];
        #pragma unroll
        for (int r = 0; r < 4; r++) {
            mnew[r]  = fmaxf(m_r[r], rmax[r]);
            alpha[r] = __expf(m_r[r] - mnew[r]);
            float a = 0.f;
            #pragma unroll
            for (int nt = 0; nt < 4; nt++) { p[nt][r] = __expf(sv[nt][r] - mnew[r]); a += p[nt][r]; }
            rsum[r] = a;
        }
        #pragma unroll
        for (int st = 1; st < 16; st <<= 1)
            #pragma unroll
            for (int r = 0; r < 4; r++)
                rsum[r] += __shfl_xor(rsum[r], st, 64);
        #pragma unroll
        for (int r = 0; r < 4; r++) {
            l_r[r] = l_r[r] * alpha[r] + rsum[r];
            m_r[r] = mnew[r];
        }
        #pragma unroll
        for (int dt = 0; dt < 5; dt++)
            #pragma unroll
            for (int r = 0; r < 4; r++)
                o_acc[dt][r] *= alpha[r];
        // P (C-layout) -> PT (A-layout)
        #pragma unroll
        for (int nt = 0; nt < 4; nt++)
            #pragma unroll
            for (int r = 0; r < 4; r++)
                PT[(quad*4 + r)*72 + nt*16 + l15] = f2b(p[nt][r]);

        // ---- PV: V B-frags b128 from VTs
        bf16x8 pa[2];
        #pragma unroll
        for (int ks = 0; ks < 2; ks++)
            pa[ks] = *(const bf16x8*)&PT[l15*72 + ks*32 + quad*8];
        #pragma unroll
        for (int dt = 0; dt < 5; dt++) {
            #pragma unroll
            for (int ks = 0; ks < 2; ks++) {
                bf16x8 vf = *(const bf16x8*)&VTs[(dt*16 + l15)*72 + ks*32 + quad*8];
                o_acc[dt] = __builtin_amdgcn_mfma_f32_16x16x32_bf16(pa[ks], vf, o_acc[dt], 0, 0, 0);
            }
        }
    }

    // ---- epilogue
    #pragma unroll
    for (int r = 0; r < 4; r++) {
        const float inv = 1.0f / l_r[r];
        size_t row_g = (size_t)(b*S_ + q0 + wv*16 + quad*4 + r);
        #pragma unroll
        for (int dt = 0; dt < 5; dt++)
            o[row_g*E_ + h*D_ + dt*16 + l15] = f2b(o_acc[dt][r] * inv);
    }
}

extern "C" void kernel_launch(void* const* d_in, const int* in_sizes, int n_in,
                              void* d_out, int out_size, void* d_ws, size_t ws_size,
                              hipStream_t stream)
{
    const float* x    = (const float*)d_in[0];
    const int*   cu   = (const int*)  d_in[1];
    const float* cosp = (const float*)d_in[2];
    const float* sinp = (const float*)d_in[3];
    const float* wq   = (const float*)d_in[4];
    const float* bq   = (const float*)d_in[5];
    const float* wk   = (const float*)d_in[6];
    const float* bk   = (const float*)d_in[7];
    const float* wv   = (const float*)d_in[8];
    const float* bv   = (const float*)d_in[9];
    const float* wo   = (const float*)d_in[10];
    const float* bo   = (const float*)d_in[11];
    float* out = (float*)d_out;

    bf16* q   = (bf16*)d_ws;
    bf16* kk  = q   + (size_t)M_ * E_;
    bf16* vt  = kk  + (size_t)M_ * E_;   // transposed V: [B][H][D][S]
    bf16* ao  = vt  + (size_t)M_ * E_;
    bf16* xb  = ao  + (size_t)M_ * E_;
    bf16* wqb = xb  + (size_t)M_ * E_;
    bf16* wkb = wqb + (size_t)E_ * E_;
    bf16* wvb = wkb + (size_t)E_ * E_;
    bf16* wob = wvb + (size_t)E_ * E_;

    // 0) convert x + 4 weight matrices to bf16
    cvt_kernel<<<dim3(2560, 5), 256, 0, stream>>>(
        x, wq, wk, wv, wo, xb, wqb, wkb, wvb, wob, M_*E_, E_*E_);

    // 1) QKV projection (MFMA, BK=64), bias fused; V written transposed.
    //    q/k hold PRE-rope values (rope fused into attention staging).
    mfma_gemm_bt<bf16, true><<<dim3(M_/128, 30), 256, 0, stream>>>(
        xb, wqb, wkb, wvb, bq, bk, bv, q, kk, vt, E_, E_, 10);

    // 2) MFMA flash attention (64-row tiles, 4 blocks/CU, XCD swizzle, fused RoPE)
    attn_mfma<<<1024, 256, 0, stream>>>(q, kk, vt, cu, cosp, sinp, ao);

    // 3) output projection (MFMA, BK=64), fp32 out, bias fused
    mfma_gemm_bt<float, false><<<dim3(M_/128, 10), 256, 0, stream>>>(
        ao, wob, wob, wob, bo, bo, bo, out, out, out, E_, E_, 10);
}

// Round 12
// 272.446 us; speedup vs baseline: 1.3220x; 1.0068x over previous
//
#include <hip/hip_runtime.h>
#include <hip/hip_bf16.h>

#define B_ 4
#define S_ 1024
#define E_ 1280
#define H_ 16
#define D_ 80
#define M_ (B_*S_)   // 4096

typedef __hip_bfloat16 bf16;
using bf16x8 = __attribute__((ext_vector_type(8))) short;  // 8 bf16 = 4 VGPRs
using f32x4  = __attribute__((ext_vector_type(4))) float;  // MFMA C/D frag

__device__ __forceinline__ float b2f(bf16 x){ return __bfloat162float(x); }
__device__ __forceinline__ bf16  f2b(float x){ return __float2bfloat16(x); }
__device__ __forceinline__ void  stf(float* p, float v){ *p = v; }
__device__ __forceinline__ void  stf(bf16*  p, float v){ *p = f2b(v); }

__device__ __forceinline__ void gload_lds16(const void* g, void* l) {
    __builtin_amdgcn_global_load_lds(
        (const __attribute__((address_space(1))) unsigned int*)g,
        (__attribute__((address_space(3))) unsigned int*)l, 16, 0, 0);
}

// fp32 -> bf16 conversion, 8 elems/thread. blockIdx.y selects segment.
__global__ __launch_bounds__(256) void cvt_kernel(
    const float* __restrict__ s0, const float* __restrict__ s1,
    const float* __restrict__ s2, const float* __restrict__ s3,
    const float* __restrict__ s4,
    bf16* __restrict__ d0, bf16* __restrict__ d1, bf16* __restrict__ d2,
    bf16* __restrict__ d3, bf16* __restrict__ d4,
    int n0, int n1)
{
    const float* s; bf16* d; int n;
    switch (blockIdx.y) {
        case 0: s = s0; d = d0; n = n0; break;
        case 1: s = s1; d = d1; n = n1; break;
        case 2: s = s2; d = d2; n = n1; break;
        case 3: s = s3; d = d3; n = n1; break;
        default: s = s4; d = d4; n = n1; break;
    }
    int i = (blockIdx.x * 256 + threadIdx.x) * 8;
    if (i >= n) return;
    float4 a = *(const float4*)(s + i);
    float4 b = *(const float4*)(s + i + 4);
    bf16 t[8];
    t[0]=f2b(a.x); t[1]=f2b(a.y); t[2]=f2b(a.z); t[3]=f2b(a.w);
    t[4]=f2b(b.x); t[5]=f2b(b.y); t[6]=f2b(b.z); t[7]=f2b(b.w);
    *(uint4*)(d + i) = *(const uint4*)t;
}

// m97-style MFMA GEMM, BK=64 (two [128][32] LDS panels per operand).
// C[m,n] = sum_k A[m,k]*W[n,k] + bias[n]
// VT_OUT: mat==2 (V) stores transposed as VT[btok][h][d][key].
template<typename TC, bool VT_OUT>
__global__ __launch_bounds__(256) void mfma_gemm_bt(
    const bf16* __restrict__ A,
    const bf16* __restrict__ W0, const bf16* __restrict__ W1, const bf16* __restrict__ W2,
    const float* __restrict__ b0, const float* __restrict__ b1, const float* __restrict__ b2,
    TC* __restrict__ C0, TC* __restrict__ C1, TC* __restrict__ C2,
    int K, int N, int ntiles)
{
    const int mat = blockIdx.y / ntiles;
    const int bn  = (blockIdx.y % ntiles) * 128;
    const int bm  = blockIdx.x * 128;
    const bf16* W; const float* bias; TC* C;
    if (mat == 0)      { W = W0; bias = b0; C = C0; }
    else if (mat == 1) { W = W1; bias = b1; C = C1; }
    else               { W = W2; bias = b2; C = C2; }

    __shared__ bf16 As[2][128][32];   // panel p covers k0 + p*32 .. +32
    __shared__ bf16 Ws[2][128][32];

    const int tid  = threadIdx.x;
    const int lane = tid & 63;
    const int wv   = tid >> 6;
    const int wm   = (wv & 1) * 64;
    const int wn   = (wv >> 1) * 64;
    const int srow = wv * 16 + (lane >> 2);
    const int scol = (lane & 3) * 8;

    f32x4 acc[4][4] = {};

    for (int k0 = 0; k0 < K; k0 += 64) {
        __syncthreads();
        #pragma unroll
        for (int p = 0; p < 2; p++) {
            const int kc = k0 + p*32 + scol;
            gload_lds16(A + (size_t)(bm + srow)      * K + kc, &As[p][wv*16][0]);
            gload_lds16(A + (size_t)(bm + 64 + srow) * K + kc, &As[p][64 + wv*16][0]);
            gload_lds16(W + (size_t)(bn + srow)      * K + kc, &Ws[p][wv*16][0]);
            gload_lds16(W + (size_t)(bn + 64 + srow) * K + kc, &Ws[p][64 + wv*16][0]);
        }
        __syncthreads();

        const int fr = lane & 15;
        const int kq = (lane >> 4) * 8;
        #pragma unroll
        for (int p = 0; p < 2; p++) {
            bf16x8 af[4], wf[4];
            #pragma unroll
            for (int t = 0; t < 4; t++) {
                af[t] = *(const bf16x8*)&As[p][wm + t*16 + fr][kq];
                wf[t] = *(const bf16x8*)&Ws[p][wn + t*16 + fr][kq];
            }
            #pragma unroll
            for (int mt = 0; mt < 4; mt++)
                #pragma unroll
                for (int nt = 0; nt < 4; nt++)
                    acc[mt][nt] = __builtin_amdgcn_mfma_f32_16x16x32_bf16(
                        af[mt], wf[nt], acc[mt][nt], 0, 0, 0);
        }
    }

    const int col_l = lane & 15;
    const int row_l = (lane >> 4) * 4;

    if (VT_OUT && mat == 2) {
        const int btok = bm >> 10;
        const int keyb = (bm & 1023) + wm + row_l;
        #pragma unroll
        for (int nt = 0; nt < 4; nt++) {
            const int n = bn + wn + nt*16 + col_l;
            const float bv = bias[n];
            const int hh = n / 80, dd = n % 80;
            bf16* vbase = (bf16*)C + ((size_t)(btok*H_ + hh)*D_ + dd)*S_ + keyb;
            #pragma unroll
            for (int mt = 0; mt < 4; mt++) {
                union { bf16 h[4]; uint2 u; } t4;
                #pragma unroll
                for (int r = 0; r < 4; r++) t4.h[r] = f2b(acc[mt][nt][r] + bv);
                *(uint2*)&vbase[mt*16] = t4.u;
            }
        }
    } else {
        #pragma unroll
        for (int nt = 0; nt < 4; nt++) {
            const int n = bn + wn + nt*16 + col_l;
            const float bv = bias[n];
            #pragma unroll
            for (int mt = 0; mt < 4; mt++) {
                #pragma unroll
                for (int r = 0; r < 4; r++) {
                    const int m = bm + wm + mt*16 + row_l + r;
                    stf(&C[(size_t)m * N + n], acc[mt][nt][r] + bv);
                }
            }
        }
    }
}

// rope helper: lo=dims j..j+8 (j<40), hi=j+40.. ; out_lo = x1*c - x2*s, out_hi = x2*c + x1*s
__device__ __forceinline__ void rope8(const bf16* lo, const bf16* hi,
                                      const float* cp, const float* sp,
                                      float mul, uint4* out_lo, uint4* out_hi)
{
    union { uint4 u; bf16 h[8]; } li, hi_, lo_o, hi_o;
    li.u  = *(const uint4*)lo;
    hi_.u = *(const uint4*)hi;
    #pragma unroll
    for (int u = 0; u < 8; u++) {
        float x1 = b2f(li.h[u]), x2 = b2f(hi_.h[u]);
        float c = cp[u], s = sp[u];
        lo_o.h[u] = f2b((x1*c - x2*s) * mul);
        hi_o.h[u] = f2b((x2*c + x1*s) * mul);
    }
    *out_lo = lo_o.u;
    *out_hi = hi_o.u;
}

// MFMA flash attention v7 — v6 + varlen tile skipping.
// lens are multiples of 64 here, so each 64-row q-tile is fully valid or
// fully invalid:
//  - valid q-tile: iterate only len/64 k-tiles, NO masking (all full).
//  - invalid q-tile (reference: uniform softmax over all 1024 keys): skip
//    Q/K/QK/softmax entirely; PT=1, PV-only over 16 tiles, normalize 1/1024.
//  - len%64 != 0 (not this instance): fall back to full 16-tile masked path.
__global__ __launch_bounds__(256, 4) void attn_mfma(
    const bf16* __restrict__ q, const bf16* __restrict__ k, const bf16* __restrict__ vt,
    const int* __restrict__ cu, const float* __restrict__ cosp, const float* __restrict__ sinp,
    bf16* __restrict__ o)
{
    // Qs[64][104] @0 (13312 B) | Ks[64][104] @13312 | VTs[80][72] @26624 (11520 B)
    // PT per-wave [16][72] (2304 B) aliases Qs (qf in regs + barrier before first PT write).
    __shared__ __align__(16) char smem[38144];
    bf16* Qs  = (bf16*)smem;
    bf16* Ks  = (bf16*)(smem + 13312);
    bf16* VTs = (bf16*)(smem + 26624);

    const int L  = blockIdx.x;
    const int qt = L >> 6;          // 0..15
    const int g  = L & 63;
    const int b  = g >> 4;
    const int h  = g & 15;

    const int tid = threadIdx.x;
    const int lane = tid & 63, wv = tid >> 6;
    const int quad = lane >> 4, l15 = lane & 15;
    const int q0 = qt * 64;
    const int len = cu[b + 1] - cu[b];
    const float scale = 0.11180339887498949f;  // 1/sqrt(80), folded into Q

    const bool uniformq = (q0 >= len);           // whole q-tile invalid
    const bool cleanlen = ((len & 63) == 0);
    const int  ktiles   = uniformq ? 16 : (cleanlen ? (len >> 6) : 16);
    const bool domask   = !uniformq && !cleanlen;

    bf16* PT = (bf16*)(smem + wv * 2304);   // [16][72], aliases Qs

    bf16x8 qf[3];
    if (!uniformq) {
        // ---- stage Q with fused RoPE (pre-scaled): 64 rows x 5 pair-chunks
        #pragma unroll
        for (int i = 0; i < 2; i++) {
            int c = tid + i * 256;
            if (c < 320) {
                int row = c / 5, pc = c % 5;
                int s = q0 + row;
                const bf16* src = q + (size_t)(b*S_ + s)*E_ + h*D_ + pc*8;
                uint4 olo, ohi;
                rope8(src, src + 40, cosp + s*D_ + pc*8, sinp + s*D_ + pc*8, scale, &olo, &ohi);
                *(uint4*)&Qs[row*104 + pc*8]      = olo;
                *(uint4*)&Qs[row*104 + (pc+5)*8]  = ohi;
            }
        }
        // zero-pad cols 80..95 (Qs + Ks)
        if (tid < 128) {
            uint4 z = make_uint4(0,0,0,0);
            int row = tid >> 1, c8 = 10 + (tid & 1);
            *(uint4*)&Qs[row*104 + c8*8] = z;
            *(uint4*)&Ks[row*104 + c8*8] = z;
        }
        __syncthreads();
        #pragma unroll
        for (int ks = 0; ks < 3; ks++)
            qf[ks] = *(const bf16x8*)&Qs[(wv*16 + l15)*104 + ks*32 + quad*8];
    } else {
        // uniform path: PT = 1 for all 16 rows x 64 cols (written once)
        const bf16 one = f2b(1.0f);
        #pragma unroll
        for (int nt = 0; nt < 4; nt++)
            #pragma unroll
            for (int r = 0; r < 4; r++)
                PT[(quad*4 + r)*72 + nt*16 + l15] = one;
    }

    float m_r[4], l_r[4];
    #pragma unroll
    for (int r = 0; r < 4; r++) { m_r[r] = -1e30f; l_r[r] = 0.f; }
    f32x4 o_acc[5] = {};

    const bool q_full = (q0 + 64) <= len;

    for (int kt = 0; kt < ktiles; kt++) {
        __syncthreads();   // prev tile LDS reads done; kt=0: qf loaded (PT/Qs alias safe)
        if (!uniformq) {
            // stage K tile with fused RoPE: 64 rows x 5 pair-chunks
            #pragma unroll
            for (int i = 0; i < 2; i++) {
                int c = tid + i * 256;
                if (c < 320) {
                    int row = c / 5, pc = c % 5;
                    int s = kt*64 + row;
                    const bf16* src = k + (size_t)(b*S_ + s)*E_ + h*D_ + pc*8;
                    uint4 olo, ohi;
                    rope8(src, src + 40, cosp + s*D_ + pc*8, sinp + s*D_ + pc*8, 1.0f, &olo, &ohi);
                    *(uint4*)&Ks[row*104 + pc*8]      = olo;
                    *(uint4*)&Ks[row*104 + (pc+5)*8]  = ohi;
                }
            }
        }
        // stage VT tile (640 chunks): VTs[d][key]
        #pragma unroll
        for (int i = 0; i < 3; i++) {
            int c = tid + i * 256;
            if (c < 640) {
                int d = c >> 3, kc = c & 7;
                *(uint4*)&VTs[d*72 + kc*8] =
                    *(const uint4*)(vt + ((size_t)(b*H_ + h)*D_ + d)*S_ + kt*64 + kc*8);
            }
        }
        __syncthreads();

        if (!uniformq) {
            // ---- QK^T: 4 n-tiles x 3 ksteps
            f32x4 s4[4];
            #pragma unroll
            for (int nt = 0; nt < 4; nt++) {
                f32x4 a0 = {};
                #pragma unroll
                for (int ks = 0; ks < 3; ks++) {
                    bf16x8 kf = *(const bf16x8*)&Ks[(nt*16 + l15)*104 + ks*32 + quad*8];
                    a0 = __builtin_amdgcn_mfma_f32_16x16x32_bf16(qf[ks], kf, a0, 0, 0, 0);
                }
                s4[nt] = a0;
            }

            // ---- online softmax (rows quad*4+r, wave-exclusive)
            float sv[4][4];
            if (!domask || (q_full && (kt*64 + 64) <= len)) {
                #pragma unroll
                for (int r = 0; r < 4; r++)
                    #pragma unroll
                    for (int nt = 0; nt < 4; nt++)
                        sv[nt][r] = s4[nt][r];
            } else {
                bool vk[4];
                #pragma unroll
                for (int nt = 0; nt < 4; nt++) vk[nt] = (kt*64 + nt*16 + l15) < len;
                #pragma unroll
                for (int r = 0; r < 4; r++) {
                    const bool vq = (q0 + wv*16 + quad*4 + r) < len;
                    #pragma unroll
                    for (int nt = 0; nt < 4; nt++)
                        sv[nt][r] = (vq && vk[nt]) ? s4[nt][r] : -1e9f;
                }
            }
            float rmax[4];
            #pragma unroll
            for (int r = 0; r < 4; r++)
                rmax[r] = fmaxf(fmaxf(sv[0][r], sv[1][r]), fmaxf(sv[2][r], sv[3][r]));
            #pragma unroll
            for (int st = 1; st < 16; st <<= 1)
                #pragma unroll
                for (int r = 0; r < 4; r++)
                    rmax[r] = fmaxf(rmax[r], __shfl_xor(rmax[r], st, 64));
            float mnew[4], alpha[4], rsum[4], p[4][4];
            #pragma unroll
            for (int r = 0; r < 4; r++) {
                mnew[r]  = fmaxf(m_r[r], rmax[r]);
                alpha[r] = __expf(m_r[r] - mnew[r]);
                float a = 0.f;
                #pragma unroll
                for (int nt = 0; nt < 4; nt++) { p[nt][r] = __expf(sv[nt][r] - mnew[r]); a += p[nt][r]; }
                rsum[r] = a;
            }
            #pragma unroll
            for (int st = 1; st < 16; st <<= 1)
                #pragma unroll
                for (int r = 0; r < 4; r++)
                    rsum[r] += __shfl_xor(rsum[r], st, 64);
            #pragma unroll
            for (int r = 0; r < 4; r++) {
                l_r[r] = l_r[r] * alpha[r] + rsum[r];
                m_r[r] = mnew[r];
            }
            #pragma unroll
            for (int dt = 0; dt < 5; dt++)
                #pragma unroll
                for (int r = 0; r < 4; r++)
                    o_acc[dt][r] *= alpha[r];
            // P (C-layout) -> PT (A-layout)
            #pragma unroll
            for (int nt = 0; nt < 4; nt++)
                #pragma unroll
                for (int r = 0; r < 4; r++)
                    PT[(quad*4 + r)*72 + nt*16 + l15] = f2b(p[nt][r]);
        }

        // ---- PV: V B-frags b128 from VTs
        bf16x8 pa[2];
        #pragma unroll
        for (int ks = 0; ks < 2; ks++)
            pa[ks] = *(const bf16x8*)&PT[l15*72 + ks*32 + quad*8];
        #pragma unroll
        for (int dt = 0; dt < 5; dt++) {
            #pragma unroll
            for (int ks = 0; ks < 2; ks++) {
                bf16x8 vf = *(const bf16x8*)&VTs[(dt*16 + l15)*72 + ks*32 + quad*8];
                o_acc[dt] = __builtin_amdgcn_mfma_f32_16x16x32_bf16(pa[ks], vf, o_acc[dt], 0, 0, 0);
            }
        }
    }

    // ---- epilogue
    #pragma unroll
    for (int r = 0; r < 4; r++) {
        const float inv = uniformq ? (1.0f / 1024.0f) : (1.0f / l_r[r]);
        size_t row_g = (size_t)(b*S_ + q0 + wv*16 + quad*4 + r);
        #pragma unroll
        for (int dt = 0; dt < 5; dt++)
            o[row_g*E_ + h*D_ + dt*16 + l15] = f2b(o_acc[dt][r] * inv);
    }
}

extern "C" void kernel_launch(void* const* d_in, const int* in_sizes, int n_in,
                              void* d_out, int out_size, void* d_ws, size_t ws_size,
                              hipStream_t stream)
{
    const float* x    = (const float*)d_in[0];
    const int*   cu   = (const int*)  d_in[1];
    const float* cosp = (const float*)d_in[2];
    const float* sinp = (const float*)d_in[3];
    const float* wq   = (const float*)d_in[4];
    const float* bq   = (const float*)d_in[5];
    const float* wk   = (const float*)d_in[6];
    const float* bk   = (const float*)d_in[7];
    const float* wv   = (const float*)d_in[8];
    const float* bv   = (const float*)d_in[9];
    const float* wo   = (const float*)d_in[10];
    const float* bo   = (const float*)d_in[11];
    float* out = (float*)d_out;

    bf16* q   = (bf16*)d_ws;
    bf16* kk  = q   + (size_t)M_ * E_;
    bf16* vt  = kk  + (size_t)M_ * E_;   // transposed V: [B][H][D][S]
    bf16* ao  = vt  + (size_t)M_ * E_;
    bf16* xb  = ao  + (size_t)M_ * E_;
    bf16* wqb = xb  + (size_t)M_ * E_;
    bf16* wkb = wqb + (size_t)E_ * E_;
    bf16* wvb = wkb + (size_t)E_ * E_;
    bf16* wob = wvb + (size_t)E_ * E_;

    // 0) convert x + 4 weight matrices to bf16
    cvt_kernel<<<dim3(2560, 5), 256, 0, stream>>>(
        x, wq, wk, wv, wo, xb, wqb, wkb, wvb, wob, M_*E_, E_*E_);

    // 1) QKV projection (MFMA, BK=64), bias fused; V written transposed.
    //    q/k hold PRE-rope values (rope fused into attention staging).
    mfma_gemm_bt<bf16, true><<<dim3(M_/128, 30), 256, 0, stream>>>(
        xb, wqb, wkb, wvb, bq, bk, bv, q, kk, vt, E_, E_, 10);

    // 2) MFMA flash attention (varlen tile skipping, 4 blocks/CU, XCD swizzle)
    attn_mfma<<<1024, 256, 0, stream>>>(q, kk, vt, cu, cosp, sinp, ao);

    // 3) output projection (MFMA, BK=64), fp32 out, bias fused
    mfma_gemm_bt<float, false><<<dim3(M_/128, 10), 256, 0, stream>>>(
        ao, wob, wob, wob, bo, bo, bo, out, out, out, E_, E_, 10);
}